// Round 3
// baseline (129.252 us; speedup 1.0000x reference)
//
#include <hip/hip_runtime.h>
#include <math.h>

#define PCNT 2048
#define CDIM 512
#define CAP_B (PCNT * 9)   // worst-case entries per batch (box spans <=3x3 cells)

// ------------------------------------------------------------------
// K1: xr = inputs @ W.T + b ; logit = softmax(xr). Weights in VGPRs.
// ------------------------------------------------------------------
__global__ __launch_bounds__(256) void k_gemv_softmax(
    const float* __restrict__ in, const float* __restrict__ W,
    const float* __restrict__ bias, float* __restrict__ out)
{
    int tid = threadIdx.x;
    int wave = tid >> 6, lane = tid & 63;
    const float4* W4 = (const float4*)W;   // 4 rows x 128 float4
    float4 w00 = W4[0 * 128 + lane], w01 = W4[0 * 128 + lane + 64];
    float4 w10 = W4[1 * 128 + lane], w11 = W4[1 * 128 + lane + 64];
    float4 w20 = W4[2 * 128 + lane], w21 = W4[2 * 128 + lane + 64];
    float4 w30 = W4[3 * 128 + lane], w31 = W4[3 * 128 + lane + 64];
    float b0 = bias[0], b1 = bias[1], b2 = bias[2], b3 = bias[3];
    int row0 = blockIdx.x * 64 + wave * 16;
    for (int r = 0; r < 16; ++r) {
        int row = row0 + r;
        const float4* ip = (const float4*)(in + (size_t)row * CDIM);
        float4 v0 = ip[lane], v1 = ip[lane + 64];
        float a0 = v0.x*w00.x + v0.y*w00.y + v0.z*w00.z + v0.w*w00.w
                 + v1.x*w01.x + v1.y*w01.y + v1.z*w01.z + v1.w*w01.w;
        float a1 = v0.x*w10.x + v0.y*w10.y + v0.z*w10.z + v0.w*w10.w
                 + v1.x*w11.x + v1.y*w11.y + v1.z*w11.z + v1.w*w11.w;
        float a2 = v0.x*w20.x + v0.y*w20.y + v0.z*w20.z + v0.w*w20.w
                 + v1.x*w21.x + v1.y*w21.y + v1.z*w21.z + v1.w*w21.w;
        float a3 = v0.x*w30.x + v0.y*w30.y + v0.z*w30.z + v0.w*w30.w
                 + v1.x*w31.x + v1.y*w31.y + v1.z*w31.z + v1.w*w31.w;
#pragma unroll
        for (int off = 1; off < 64; off <<= 1) {
            a0 += __shfl_xor(a0, off, 64);
            a1 += __shfl_xor(a1, off, 64);
            a2 += __shfl_xor(a2, off, 64);
            a3 += __shfl_xor(a3, off, 64);
        }
        if (lane == 0) {
            a0 += b0; a1 += b1; a2 += b2; a3 += b3;
            float m = fmaxf(fmaxf(a0, a1), fmaxf(a2, a3));
            float e0 = expf(a0 - m), e1 = expf(a1 - m), e2 = expf(a2 - m), e3 = expf(a3 - m);
            float inv = 1.f / (e0 + e1 + e2 + e3);
            ((float4*)out)[row] = make_float4(e0 * inv, e1 * inv, e2 * inv, e3 * inv);
        }
    }
}

// ------------------------------------------------------------------
// K2: seeds. One block per (b,c). Per-class seed plane (0/1).
// ------------------------------------------------------------------
__global__ __launch_bounds__(256) void k_seeds(
    const float* __restrict__ ps, unsigned char* __restrict__ planes, int B)
{
    int b = blockIdx.x / 3, c = blockIdx.x % 3;
    int tid = threadIdx.x;
    __shared__ float sval[256];
    __shared__ int   sidx[256];
    __shared__ int   scnt[256];

    float bestv = -1e30f; int besti = 0; int cnt = 0;
#pragma unroll
    for (int t = 0; t < PCNT / 256; ++t) {
        int j = tid + t * 256;
        float v = ps[((size_t)b * PCNT + j) * 4 + c];
        if (v > 0.5f) cnt++;
        if (v > bestv) { bestv = v; besti = j; }
    }
    sval[tid] = bestv; sidx[tid] = besti; scnt[tid] = cnt;
    __syncthreads();
    for (int s = 128; s > 0; s >>= 1) {
        if (tid < s) {
            float v2 = sval[tid + s]; int i2 = sidx[tid + s];
            if (v2 > sval[tid] || (v2 == sval[tid] && i2 < sidx[tid])) { sval[tid] = v2; sidx[tid] = i2; }
            scnt[tid] += scnt[tid + s];
        }
        __syncthreads();
    }
    int totcnt = scnt[0];
    int amax   = sidx[0];
    unsigned char* pl = planes + ((size_t)c * B + b) * PCNT;
#pragma unroll
    for (int t = 0; t < PCNT / 256; ++t) {
        int j = tid + t * 256;
        float v = ps[((size_t)b * PCNT + j) * 4 + c];
        bool bit = (totcnt <= 1) ? (j == amax) : (v > 0.5f);
        pl[j] = bit ? 1 : 0;
    }
}

// ------------------------------------------------------------------
// K3: spatial binning of union-seeded boxes. One block per batch.
// 8x8 grid of 128-px cells. Entry = float4 box + float4(m0,m1,m2,j).
// ------------------------------------------------------------------
__global__ __launch_bounds__(256) void k_bin(
    const float* __restrict__ rois, const unsigned char* __restrict__ planes,
    int* __restrict__ cellStart, int* __restrict__ cellCnt,
    float4* __restrict__ roisE, float4* __restrict__ metaE, int B)
{
    __shared__ int cnt[64], st[64], cur[64];
    int b = blockIdx.x, tid = threadIdx.x;
    if (tid < 64) cnt[tid] = 0;
    __syncthreads();
    const float4* rb = (const float4*)(rois + (size_t)b * PCNT * 4);
    const unsigned char* pl0 = planes + (size_t)b * PCNT;
    const unsigned char* pl1 = planes + ((size_t)B + b) * PCNT;
    const unsigned char* pl2 = planes + ((size_t)2 * B + b) * PCNT;

    for (int j = tid; j < PCNT; j += 256) {
        int m = pl0[j] | pl1[j] | pl2[j];
        if (!m) continue;
        float4 q = rb[j];
        int cx0 = ((int)q.x) >> 7, cx1 = ((int)q.z) >> 7;
        int cy0 = ((int)q.y) >> 7, cy1 = ((int)q.w) >> 7;
        for (int cy = cy0; cy <= cy1; ++cy)
            for (int cx = cx0; cx <= cx1; ++cx)
                atomicAdd(&cnt[cy * 8 + cx], 1);
    }
    __syncthreads();
    if (tid == 0) {
        int a = 0;
        for (int k = 0; k < 64; ++k) { st[k] = a; a += cnt[k]; }
    }
    __syncthreads();
    if (tid < 64) {
        cur[tid] = st[tid];
        cellStart[b * 64 + tid] = st[tid];
        cellCnt[b * 64 + tid]   = cnt[tid];
    }
    __syncthreads();
    for (int j = tid; j < PCNT; j += 256) {
        int m0 = pl0[j], m1 = pl1[j], m2 = pl2[j];
        if (!(m0 | m1 | m2)) continue;
        float4 q = rb[j];
        float4 meta = make_float4((float)m0, (float)m1, (float)m2, __int_as_float(j));
        int cx0 = ((int)q.x) >> 7, cx1 = ((int)q.z) >> 7;
        int cy0 = ((int)q.y) >> 7, cy1 = ((int)q.w) >> 7;
        for (int cy = cy0; cy <= cy1; ++cy)
            for (int cx = cx0; cx <= cx1; ++cx) {
                int e = atomicAdd(&cur[cy * 8 + cx], 1);
                size_t idx = (size_t)b * CAP_B + e;
                roisE[idx] = q;
                metaE[idx] = meta;
            }
    }
}

// ------------------------------------------------------------------
// K4: assignment via cell lists. 8 lanes per i; exact (max, min-j).
// Duplicates across cells are idempotent; order-independent result.
// ------------------------------------------------------------------
__global__ __launch_bounds__(512, 4) void k_assign_cells(
    const float* __restrict__ rois, const float* __restrict__ ps,
    const float* __restrict__ labels,
    const int* __restrict__ cellStart, const int* __restrict__ cellCnt,
    const float4* __restrict__ roisE, const float4* __restrict__ metaE,
    int* __restrict__ cls_out, float* __restrict__ wrow_out, int* __restrict__ imb)
{
    __shared__ int hist[4];
    int b    = blockIdx.x >> 5;
    int tile = blockIdx.x & 31;
    int tid  = threadIdx.x;
    if (tid < 4) hist[tid] = 0;
    __syncthreads();

    int i  = tile * 64 + (tid >> 3);
    int jq = tid & 7;
    float4 r = ((const float4*)rois)[(size_t)b * PCNT + i];
    float areaA = (r.z - r.x) * (r.w - r.y);
    int cx0 = ((int)r.x) >> 7, cx1 = ((int)r.z) >> 7;
    int cy0 = ((int)r.y) >> 7, cy1 = ((int)r.w) >> 7;

    float best0 = -1.f, best1 = -1.f, best2 = -1.f;
    int   bj0 = 1 << 30, bj1 = 1 << 30, bj2 = 1 << 30;

    for (int cy = cy0; cy <= cy1; ++cy)
    for (int cx = cx0; cx <= cx1; ++cx) {
        int cell = b * 64 + cy * 8 + cx;
        int s = cellStart[cell], n = cellCnt[cell];
        size_t base = (size_t)b * CAP_B + s;
        for (int e = jq; e < n; e += 8) {
            float4 q = roisE[base + e];
            float4 m = metaE[base + e];
            float lx = fmaxf(r.x, q.x), ly = fmaxf(r.y, q.y);
            float rx = fminf(r.z, q.z), ry = fminf(r.w, q.w);
            float ww = fmaxf(rx - lx, 0.f);
            float hh = fmaxf(ry - ly, 0.f);
            float inter = ww * hh;
            float areaB = (q.z - q.x) * (q.w - q.y);
            float u = (areaA + areaB) - inter;
            float ioup1 = fmaf(inter, __builtin_amdgcn_rcpf(u), 1.0f); // iou+1
            int j = __float_as_int(m.w);
            float t0 = fmaf(ioup1, m.x, -1.0f);
            if (t0 > best0 || (t0 == best0 && j < bj0)) { best0 = t0; bj0 = j; }
            float t1 = fmaf(ioup1, m.y, -1.0f);
            if (t1 > best1 || (t1 == best1 && j < bj1)) { best1 = t1; bj1 = j; }
            float t2 = fmaf(ioup1, m.z, -1.0f);
            if (t2 > best2 || (t2 == best2 && j < bj2)) { best2 = t2; bj2 = j; }
        }
    }

#pragma unroll
    for (int off = 1; off < 8; off <<= 1) {
        float v; int j2;
        v = __shfl_xor(best0, off, 64); j2 = __shfl_xor(bj0, off, 64);
        if (v > best0 || (v == best0 && j2 < bj0)) { best0 = v; bj0 = j2; }
        v = __shfl_xor(best1, off, 64); j2 = __shfl_xor(bj1, off, 64);
        if (v > best1 || (v == best1 && j2 < bj1)) { best1 = v; bj1 = j2; }
        v = __shfl_xor(best2, off, 64); j2 = __shfl_xor(bj2, off, 64);
        if (v > best2 || (v == best2 && j2 < bj2)) { best2 = v; bj2 = j2; }
    }

    if (jq == 0) {
        bj0 = (bj0 < PCNT) ? bj0 : 0;
        bj1 = (bj1 < PCNT) ? bj1 : 0;
        bj2 = (bj2 < PCNT) ? bj2 : 0;
        float lab0 = labels[b * 4 + 0];
        float lab1 = labels[b * 4 + 1];
        float lab2 = labels[b * 4 + 2];
        float x0 = ps[((size_t)b * PCNT + bj0) * 4 + 0];
        float x1 = ps[((size_t)b * PCNT + bj1) * 4 + 1];
        float x2 = ps[((size_t)b * PCNT + bj2) * 4 + 2];
        float I = -1.f; int cls = 3; float wv = 1.f;
        if (lab0 > 0.f && best0 >= 0.5f && best0 > I) { I = best0; wv = x0; cls = 0; }
        if (lab1 > 0.f && best1 >= 0.5f && best1 > I) { I = best1; wv = x1; cls = 1; }
        if (lab2 > 0.f && best2 >= 0.5f && best2 > I) { I = best2; wv = x2; cls = 2; }
        int row = b * PCNT + i;
        cls_out[row]  = cls;
        wrow_out[row] = wv;
        atomicAdd(&hist[cls], 1);
    }
    __syncthreads();
    if (tid < 4 && hist[tid] > 0) atomicAdd(&imb[tid], hist[tid]);
}

// ------------------------------------------------------------------
// K4-fallback (R2 path, used only if ws too small): full scan.
// ------------------------------------------------------------------
__global__ __launch_bounds__(512, 4) void k_assign_full(
    const float* __restrict__ rois, const float* __restrict__ ps,
    const float* __restrict__ labels, const unsigned char* __restrict__ planes,
    int* __restrict__ cls_out, float* __restrict__ wrow_out, int* __restrict__ imb,
    int B)
{
    __shared__ float4 lrois[1024];
    __shared__ float4 lmeta[1024];
    __shared__ int hist[4];

    int b    = blockIdx.x >> 5;
    int tile = blockIdx.x & 31;
    int tid  = threadIdx.x;
    if (tid < 4) hist[tid] = 0;

    const float4* rb = (const float4*)(rois + (size_t)b * PCNT * 4);
    const unsigned char* pl0 = planes + (size_t)b * PCNT;
    const unsigned char* pl1 = planes + ((size_t)B + b) * PCNT;
    const unsigned char* pl2 = planes + ((size_t)2 * B + b) * PCNT;

    int i  = tile * 64 + (tid >> 3);
    int jq = tid & 7;
    float4 r = rb[i];
    float areaA = (r.z - r.x) * (r.w - r.y);

    float best0 = -1.f, best1 = -1.f, best2 = -1.f;
    int   bj0 = 0, bj1 = 0, bj2 = 0;

    for (int ph = 0; ph < 2; ++ph) {
        __syncthreads();
        for (int jl = tid; jl < 1024; jl += 512) {
            int j = ph * 1024 + jl;
            float4 q = rb[j];
            lrois[jl] = q;
            lmeta[jl] = make_float4((q.z - q.x) * (q.w - q.y),
                                    (float)pl0[j], (float)pl1[j], (float)pl2[j]);
        }
        __syncthreads();
#pragma unroll 4
        for (int jj = 0; jj < 128; ++jj) {
            int jl = jj * 8 + jq;
            float4 q = lrois[jl];
            float4 m = lmeta[jl];
            float lx = fmaxf(r.x, q.x), ly = fmaxf(r.y, q.y);
            float rx = fminf(r.z, q.z), ry = fminf(r.w, q.w);
            float ww = fmaxf(rx - lx, 0.f);
            float hh = fmaxf(ry - ly, 0.f);
            float inter = ww * hh;
            float u = (areaA + m.x) - inter;
            float ioup1 = fmaf(inter, __builtin_amdgcn_rcpf(u), 1.0f);
            int j = ph * 1024 + jl;
            float t0 = fmaf(ioup1, m.y, -1.0f);
            if (t0 > best0) { best0 = t0; bj0 = j; }
            float t1 = fmaf(ioup1, m.z, -1.0f);
            if (t1 > best1) { best1 = t1; bj1 = j; }
            float t2 = fmaf(ioup1, m.w, -1.0f);
            if (t2 > best2) { best2 = t2; bj2 = j; }
        }
    }
#pragma unroll
    for (int off = 1; off < 8; off <<= 1) {
        float v; int j2;
        v = __shfl_xor(best0, off, 64); j2 = __shfl_xor(bj0, off, 64);
        if (v > best0 || (v == best0 && j2 < bj0)) { best0 = v; bj0 = j2; }
        v = __shfl_xor(best1, off, 64); j2 = __shfl_xor(bj1, off, 64);
        if (v > best1 || (v == best1 && j2 < bj1)) { best1 = v; bj1 = j2; }
        v = __shfl_xor(best2, off, 64); j2 = __shfl_xor(bj2, off, 64);
        if (v > best2 || (v == best2 && j2 < bj2)) { best2 = v; bj2 = j2; }
    }
    if (jq == 0) {
        float lab0 = labels[b * 4 + 0];
        float lab1 = labels[b * 4 + 1];
        float lab2 = labels[b * 4 + 2];
        float x0 = ps[((size_t)b * PCNT + bj0) * 4 + 0];
        float x1 = ps[((size_t)b * PCNT + bj1) * 4 + 1];
        float x2 = ps[((size_t)b * PCNT + bj2) * 4 + 2];
        float I = -1.f; int cls = 3; float wv = 1.f;
        if (lab0 > 0.f && best0 >= 0.5f && best0 > I) { I = best0; wv = x0; cls = 0; }
        if (lab1 > 0.f && best1 >= 0.5f && best1 > I) { I = best1; wv = x1; cls = 1; }
        if (lab2 > 0.f && best2 >= 0.5f && best2 > I) { I = best2; wv = x2; cls = 2; }
        int row = b * PCNT + i;
        cls_out[row]  = cls;
        wrow_out[row] = wv;
        atomicAdd(&hist[cls], 1);
    }
    __syncthreads();
    if (tid < 4 && hist[tid] > 0) atomicAdd(&imb[tid], hist[tid]);
}

// ------------------------------------------------------------------
// K5/K6: deterministic loss reduction
// ------------------------------------------------------------------
__global__ __launch_bounds__(256) void k_loss_partial(
    const float* __restrict__ logit, const float* __restrict__ labels,
    const int* __restrict__ cls, const float* __restrict__ wrow,
    const int* __restrict__ imb, float* __restrict__ partials, int rows)
{
    __shared__ float simb[4];
    __shared__ float sred[256];
    int tid = threadIdx.x;
    if (tid < 4) simb[tid] = (float)imb[tid] + 1e-7f;
    __syncthreads();
    float sum = 0.f;
    for (int row = blockIdx.x * 256 + tid; row < rows; row += gridDim.x * 256) {
        int k = cls[row];
        float w = wrow[row];
        int b = row >> 11;
        float l = logit[row * 4 + k];
        float p = fminf(fmaxf(l, 1e-7f), 1.f - 1e-7f);
        float om = 1.f - p;
        float fl = -logf(p) * om * om;
        float lab = (k == 3) ? 1.f : labels[b * 4 + k];
        float wu = 10.f * expf(l) * (1.f - lab) + lab;
        sum += w * fl / simb[k] * wu;
    }
    sred[tid] = sum;
    __syncthreads();
    for (int s = 128; s > 0; s >>= 1) {
        if (tid < s) sred[tid] += sred[tid + s];
        __syncthreads();
    }
    if (tid == 0) partials[blockIdx.x] = sred[0];
}

__global__ __launch_bounds__(128) void k_loss_final(
    const float* __restrict__ partials, float* __restrict__ out_loss,
    int nblk, float invB)
{
    __shared__ float sred[128];
    int tid = threadIdx.x;
    sred[tid] = (tid < nblk) ? partials[tid] : 0.f;
    __syncthreads();
    for (int s = 64; s > 0; s >>= 1) {
        if (tid < s) sred[tid] += sred[tid + s];
        __syncthreads();
    }
    if (tid == 0) *out_loss = sred[0] * invB;
}

extern "C" void kernel_launch(void* const* d_in, const int* in_sizes, int n_in,
                              void* d_out, int out_size, void* d_ws, size_t ws_size,
                              hipStream_t stream)
{
    const float* inputs = (const float*)d_in[0];
    const float* ps     = (const float*)d_in[1];
    const float* labels = (const float*)d_in[2];
    const float* rois   = (const float*)d_in[3];
    const float* fcw    = (const float*)d_in[4];
    const float* fcb    = (const float*)d_in[5];

    int B = in_sizes[2] / 4;            // 16
    int P = in_sizes[1] / (4 * B);      // 2048
    int rows = B * P;                   // 32768
    float* out = (float*)d_out;

    char* ws = (char*)d_ws;
    size_t off = 0;
    int*   imb      = (int*)(ws + off);           off += 256;
    float* partials = (float*)(ws + off);         off += 1024;
    unsigned char* planes = (unsigned char*)(ws + off); off += (size_t)3 * rows;
    off = (off + 255) & ~(size_t)255;
    int*   cls  = (int*)(ws + off);               off += (size_t)rows * 4;
    float* wrow = (float*)(ws + off);             off += (size_t)rows * 4;
    int* cellStart = (int*)(ws + off);            off += (size_t)B * 64 * 4;
    int* cellCnt   = (int*)(ws + off);            off += (size_t)B * 64 * 4;
    off = (off + 255) & ~(size_t)255;
    float4* roisE = (float4*)(ws + off);          off += (size_t)B * CAP_B * 16;
    float4* metaE = (float4*)(ws + off);          off += (size_t)B * CAP_B * 16;
    bool binned = (ws_size >= off);

    hipMemsetAsync(imb, 0, 16, stream);
    k_gemv_softmax<<<rows / 64, 256, 0, stream>>>(inputs, fcw, fcb, out);
    k_seeds<<<B * 3, 256, 0, stream>>>(ps, planes, B);
    if (binned) {
        k_bin<<<B, 256, 0, stream>>>(rois, planes, cellStart, cellCnt, roisE, metaE, B);
        k_assign_cells<<<B * (P / 64), 512, 0, stream>>>(rois, ps, labels, cellStart, cellCnt,
                                                         roisE, metaE, cls, wrow, imb);
    } else {
        k_assign_full<<<B * (P / 64), 512, 0, stream>>>(rois, ps, labels, planes, cls, wrow, imb, B);
    }
    const int NBLK = 128;
    k_loss_partial<<<NBLK, 256, 0, stream>>>(out, labels, cls, wrow, imb, partials, rows);
    k_loss_final<<<1, 128, 0, stream>>>(partials, out + (size_t)rows * 4, NBLK, 1.f / (float)B);
}

// Round 4
// 110.095 us; speedup vs baseline: 1.1740x; 1.1740x over previous
//
#include <hip/hip_runtime.h>
#include <math.h>

#define PCNT 2048
#define CDIM 512
#define CAP_B (PCNT * 9)   // worst-case entries/batch (box spans <=3x3 of the 8x8 128px cells)

// ------------------------------------------------------------------
// K1: xr = inputs @ W.T + b ; logit = softmax(xr) -> out[row*4+c]
// 16 lanes per row, 4 rows per wave, 16 rows per 256-thr block.
// W staged in LDS swizzled so lane-k b128 reads are conflict-free.
// ------------------------------------------------------------------
__global__ __launch_bounds__(256) void k_gemv_softmax(
    const float* __restrict__ in, const float* __restrict__ W,
    const float* __restrict__ bias, float* __restrict__ out)
{
    __shared__ float4 w_lds[512];   // [(m*4+c)*16 + k] = W[c][k*32 + m*4 .. +3]
    int tid = threadIdx.x;
    const float4* W4 = (const float4*)W;   // [c*128 + q]
    for (int e = tid; e < 512; e += 256) {
        int m = e >> 6, rem = e & 63, c = rem >> 4, k = rem & 15;
        w_lds[e] = W4[c * 128 + k * 8 + m];
    }
    __syncthreads();
    int row = blockIdx.x * 16 + (tid >> 4);
    int k   = tid & 15;
    const float4* ip = (const float4*)(in + (size_t)row * CDIM);
    float4 v[8];
#pragma unroll
    for (int m = 0; m < 8; ++m) v[m] = ip[k * 8 + m];
    float a0 = 0.f, a1 = 0.f, a2 = 0.f, a3 = 0.f;
#pragma unroll
    for (int m = 0; m < 8; ++m) {
        float4 w0 = w_lds[(m * 4 + 0) * 16 + k];
        float4 w1 = w_lds[(m * 4 + 1) * 16 + k];
        float4 w2 = w_lds[(m * 4 + 2) * 16 + k];
        float4 w3 = w_lds[(m * 4 + 3) * 16 + k];
        a0 += v[m].x*w0.x + v[m].y*w0.y + v[m].z*w0.z + v[m].w*w0.w;
        a1 += v[m].x*w1.x + v[m].y*w1.y + v[m].z*w1.z + v[m].w*w1.w;
        a2 += v[m].x*w2.x + v[m].y*w2.y + v[m].z*w2.z + v[m].w*w2.w;
        a3 += v[m].x*w3.x + v[m].y*w3.y + v[m].z*w3.z + v[m].w*w3.w;
    }
#pragma unroll
    for (int off = 1; off < 16; off <<= 1) {
        a0 += __shfl_xor(a0, off, 64);
        a1 += __shfl_xor(a1, off, 64);
        a2 += __shfl_xor(a2, off, 64);
        a3 += __shfl_xor(a3, off, 64);
    }
    if (k == 0) {
        a0 += bias[0]; a1 += bias[1]; a2 += bias[2]; a3 += bias[3];
        float m = fmaxf(fmaxf(a0, a1), fmaxf(a2, a3));
        float e0 = expf(a0 - m), e1 = expf(a1 - m), e2 = expf(a2 - m), e3 = expf(a3 - m);
        float inv = 1.f / (e0 + e1 + e2 + e3);
        ((float4*)out)[row] = make_float4(e0 * inv, e1 * inv, e2 * inv, e3 * inv);
    }
}

// ------------------------------------------------------------------
// K2: fused seeds + spatial binning. One 1024-thr block per batch.
// Seed rule per class c: cnt = #(sc>0.5); seed = (cnt<=1) ? (j==first_argmax)
// : (sc>0.5). Then bin ALL boxes into 8x8 grid of 128px cells with
// meta = (m0,m1,m2, j_bits).
// ------------------------------------------------------------------
__global__ __launch_bounds__(1024) void k_bin(
    const float* __restrict__ rois, const float* __restrict__ ps,
    int* __restrict__ cellStart, int* __restrict__ cellCnt,
    float4* __restrict__ roisE, float4* __restrict__ metaE)
{
    __shared__ float sval[3][1024];
    __shared__ int   sidx[3][1024];
    __shared__ int   scnt[3][1024];
    __shared__ int   amax[3], totc[3];
    __shared__ int   cnt64[64], st64[64], cur64[64];

    int b = blockIdx.x, tid = threadIdx.x;
    const float4* psb = (const float4*)ps + (size_t)b * PCNT;
    const float4* rb  = (const float4*)rois + (size_t)b * PCNT;

    float4 p1 = psb[tid], p2 = psb[tid + 1024];
    {
        // class 0 (.x), 1 (.y), 2 (.z)
        float v1, v2; int take;
        v1 = p1.x; v2 = p2.x; take = v2 > v1;
        sval[0][tid] = take ? v2 : v1; sidx[0][tid] = take ? tid + 1024 : tid;
        scnt[0][tid] = (v1 > 0.5f) + (v2 > 0.5f);
        v1 = p1.y; v2 = p2.y; take = v2 > v1;
        sval[1][tid] = take ? v2 : v1; sidx[1][tid] = take ? tid + 1024 : tid;
        scnt[1][tid] = (v1 > 0.5f) + (v2 > 0.5f);
        v1 = p1.z; v2 = p2.z; take = v2 > v1;
        sval[2][tid] = take ? v2 : v1; sidx[2][tid] = take ? tid + 1024 : tid;
        scnt[2][tid] = (v1 > 0.5f) + (v2 > 0.5f);
    }
    __syncthreads();
    for (int s = 512; s > 0; s >>= 1) {
        if (tid < s) {
#pragma unroll
            for (int c = 0; c < 3; ++c) {
                float v2 = sval[c][tid + s]; int i2 = sidx[c][tid + s];
                if (v2 > sval[c][tid] || (v2 == sval[c][tid] && i2 < sidx[c][tid])) {
                    sval[c][tid] = v2; sidx[c][tid] = i2;
                }
                scnt[c][tid] += scnt[c][tid + s];
            }
        }
        __syncthreads();
    }
    if (tid < 3) { amax[tid] = sidx[tid][0]; totc[tid] = scnt[tid][0]; }
    if (tid < 64) cnt64[tid] = 0;
    __syncthreads();

    // count pass (all boxes)
    for (int j = tid; j < PCNT; j += 1024) {
        float4 q = rb[j];
        int cx0 = ((int)q.x) >> 7, cx1 = ((int)q.z) >> 7;
        int cy0 = ((int)q.y) >> 7, cy1 = ((int)q.w) >> 7;
        for (int cy = cy0; cy <= cy1; ++cy)
            for (int cx = cx0; cx <= cx1; ++cx)
                atomicAdd(&cnt64[cy * 8 + cx], 1);
    }
    __syncthreads();
    if (tid == 0) {
        int a = 0;
        for (int kk = 0; kk < 64; ++kk) { st64[kk] = a; a += cnt64[kk]; }
    }
    __syncthreads();
    if (tid < 64) {
        cur64[tid] = st64[tid];
        cellStart[b * 64 + tid] = st64[tid];
        cellCnt[b * 64 + tid]   = cnt64[tid];
    }
    __syncthreads();

    // scatter pass
    for (int j = tid; j < PCNT; j += 1024) {
        float4 q  = rb[j];
        float4 pv = psb[j];
        float m0 = ((totc[0] <= 1) ? (j == amax[0]) : (pv.x > 0.5f)) ? 1.f : 0.f;
        float m1 = ((totc[1] <= 1) ? (j == amax[1]) : (pv.y > 0.5f)) ? 1.f : 0.f;
        float m2 = ((totc[2] <= 1) ? (j == amax[2]) : (pv.z > 0.5f)) ? 1.f : 0.f;
        float4 meta = make_float4(m0, m1, m2, __int_as_float(j));
        int cx0 = ((int)q.x) >> 7, cx1 = ((int)q.z) >> 7;
        int cy0 = ((int)q.y) >> 7, cy1 = ((int)q.w) >> 7;
        for (int cy = cy0; cy <= cy1; ++cy)
            for (int cx = cx0; cx <= cx1; ++cx) {
                int e = atomicAdd(&cur64[cy * 8 + cx], 1);
                size_t idx = (size_t)b * CAP_B + e;
                roisE[idx] = q;
                metaE[idx] = meta;
            }
    }
}

// ------------------------------------------------------------------
// K3: block per (b, cell). Cell list = both j-list (LDS-staged,
// scanned by 4 j-lanes per i) and i-list. Per-class results merged
// into global keys[] via 64-bit atomicMax (order-independent).
// key = (f32bits(iou) << 32) | (0x7FFFFFFF - j)  -> max iou, min j.
// ------------------------------------------------------------------
__global__ __launch_bounds__(512) void k_assign_cells2(
    const int* __restrict__ cellStart, const int* __restrict__ cellCnt,
    const float4* __restrict__ roisE, const float4* __restrict__ metaE,
    unsigned long long* __restrict__ keys)
{
    __shared__ float4 ldsR[512];
    __shared__ float4 ldsM[512];

    int b    = blockIdx.x >> 6;
    int cell = blockIdx.x & 63;
    int tid  = threadIdx.x;
    int n    = cellCnt[b * 64 + cell];
    if (n == 0) return;
    size_t gbase = (size_t)b * CAP_B + cellStart[b * 64 + cell];

    for (int c0 = 0; c0 < n; c0 += 512) {
        int nc = min(512, n - c0);
        __syncthreads();
        for (int kk = tid; kk < nc; kk += 512) {
            ldsR[kk] = roisE[gbase + c0 + kk];
            ldsM[kk] = metaE[gbase + c0 + kk];
        }
        __syncthreads();

        for (int ibase = 0; ibase < n; ibase += 128) {
            int idx = ibase + (tid >> 2);
            bool valid = idx < n;
            int iidx = valid ? idx : 0;
            float4 r = roisE[gbase + iidx];
            int i = __float_as_int(metaE[gbase + iidx].w);
            float areaA = (r.z - r.x) * (r.w - r.y);

            float best0 = -1.f, best1 = -1.f, best2 = -1.f;
            int   bj0 = 0, bj1 = 0, bj2 = 0;
            for (int e = tid & 3; e < nc; e += 4) {
                float4 q = ldsR[e];
                float4 m = ldsM[e];
                float lx = fmaxf(r.x, q.x), ly = fmaxf(r.y, q.y);
                float rx = fminf(r.z, q.z), ry = fminf(r.w, q.w);
                float ww = fmaxf(rx - lx, 0.f);
                float hh = fmaxf(ry - ly, 0.f);
                float inter = ww * hh;
                float areaB = (q.z - q.x) * (q.w - q.y);
                float u = (areaA + areaB) - inter;
                float ioup1 = fmaf(inter, __builtin_amdgcn_rcpf(u), 1.0f); // iou+1
                int j = __float_as_int(m.w);
                float t0 = fmaf(ioup1, m.x, -1.0f);
                if (t0 > best0 || (t0 == best0 && j < bj0)) { best0 = t0; bj0 = j; }
                float t1 = fmaf(ioup1, m.y, -1.0f);
                if (t1 > best1 || (t1 == best1 && j < bj1)) { best1 = t1; bj1 = j; }
                float t2 = fmaf(ioup1, m.z, -1.0f);
                if (t2 > best2 || (t2 == best2 && j < bj2)) { best2 = t2; bj2 = j; }
            }
#pragma unroll
            for (int off = 1; off < 4; off <<= 1) {
                float v; int j2;
                v = __shfl_xor(best0, off, 64); j2 = __shfl_xor(bj0, off, 64);
                if (v > best0 || (v == best0 && j2 < bj0)) { best0 = v; bj0 = j2; }
                v = __shfl_xor(best1, off, 64); j2 = __shfl_xor(bj1, off, 64);
                if (v > best1 || (v == best1 && j2 < bj1)) { best1 = v; bj1 = j2; }
                v = __shfl_xor(best2, off, 64); j2 = __shfl_xor(bj2, off, 64);
                if (v > best2 || (v == best2 && j2 < bj2)) { best2 = v; bj2 = j2; }
            }
            if ((tid & 3) == 0 && valid) {
                size_t kb = ((size_t)b * PCNT + i) * 3;
                if (best0 >= 0.f)
                    atomicMax(&keys[kb + 0],
                        (((unsigned long long)__float_as_uint(best0)) << 32) | (unsigned)(0x7FFFFFFF - bj0));
                if (best1 >= 0.f)
                    atomicMax(&keys[kb + 1],
                        (((unsigned long long)__float_as_uint(best1)) << 32) | (unsigned)(0x7FFFFFFF - bj1));
                if (best2 >= 0.f)
                    atomicMax(&keys[kb + 2],
                        (((unsigned long long)__float_as_uint(best2)) << 32) | (unsigned)(0x7FFFFFFF - bj2));
            }
        }
    }
}

// ------------------------------------------------------------------
// K4: finalize assignment + per-class partial loss sums/counts.
// partials[blk][0..3] = sum of w*fl*wu per class; [4..7] = counts.
// ------------------------------------------------------------------
__global__ __launch_bounds__(256) void k_finalize_loss(
    const unsigned long long* __restrict__ keys, const float* __restrict__ ps,
    const float* __restrict__ labels, const float* __restrict__ logit,
    float* __restrict__ partials, int rows)
{
    int tid = threadIdx.x;
    int row = blockIdx.x * 256 + tid;
    float s0 = 0.f, s1 = 0.f, s2 = 0.f, s3 = 0.f;
    float c0 = 0.f, c1 = 0.f, c2 = 0.f, c3 = 0.f;
    if (row < rows) {
        int b = row >> 11;   // P = 2048
        float I = -1.f; int cls = 3; float wv = 1.f;
#pragma unroll
        for (int c = 0; c < 3; ++c) {
            unsigned long long key = keys[(size_t)row * 3 + c];
            float lab = labels[b * 4 + c];
            if (key != 0ull && lab > 0.f) {
                float t = __uint_as_float((unsigned)(key >> 32));
                if (t >= 0.5f && t > I) {
                    int j = 0x7FFFFFFF - (int)(key & 0xFFFFFFFFull);
                    I = t; cls = c;
                    wv = ps[((size_t)b * PCNT + j) * 4 + c];
                }
            }
        }
        float4 lg = ((const float4*)logit)[row];
        float l = (cls == 0) ? lg.x : (cls == 1) ? lg.y : (cls == 2) ? lg.z : lg.w;
        float p = fminf(fmaxf(l, 1e-7f), 1.f - 1e-7f);
        float om = 1.f - p;
        float fl = -logf(p) * om * om;
        float lab = (cls == 3) ? 1.f : labels[b * 4 + cls];
        float wu = 10.f * expf(l) * (1.f - lab) + lab;
        float contrib = wv * fl * wu;
        s0 = (cls == 0) ? contrib : 0.f; c0 = (cls == 0) ? 1.f : 0.f;
        s1 = (cls == 1) ? contrib : 0.f; c1 = (cls == 1) ? 1.f : 0.f;
        s2 = (cls == 2) ? contrib : 0.f; c2 = (cls == 2) ? 1.f : 0.f;
        s3 = (cls == 3) ? contrib : 0.f; c3 = (cls == 3) ? 1.f : 0.f;
    }
    __shared__ float red[256];
    float vals[8] = {s0, s1, s2, s3, c0, c1, c2, c3};
#pragma unroll
    for (int comp = 0; comp < 8; ++comp) {
        red[tid] = vals[comp];
        __syncthreads();
        for (int s = 128; s > 0; s >>= 1) {
            if (tid < s) red[tid] += red[tid + s];
            __syncthreads();
        }
        if (tid == 0) partials[blockIdx.x * 8 + comp] = red[0];
        __syncthreads();
    }
}

// ------------------------------------------------------------------
// K5: final reduce: loss = sum_c S_c / (N_c + 1e-7) / B
// ------------------------------------------------------------------
__global__ __launch_bounds__(128) void k_loss_final2(
    const float* __restrict__ partials, float* __restrict__ out_loss,
    int nblk, float invB)
{
    int tid = threadIdx.x;
    __shared__ float red[128];
    float acc[8];
#pragma unroll
    for (int comp = 0; comp < 8; ++comp) {
        red[tid] = (tid < nblk) ? partials[tid * 8 + comp] : 0.f;
        __syncthreads();
        for (int s = 64; s > 0; s >>= 1) {
            if (tid < s) red[tid] += red[tid + s];
            __syncthreads();
        }
        acc[comp] = red[0];
        __syncthreads();
    }
    if (tid == 0) {
        float loss = 0.f;
#pragma unroll
        for (int c = 0; c < 4; ++c) loss += acc[c] / (acc[4 + c] + 1e-7f);
        *out_loss = loss * invB;
    }
}

extern "C" void kernel_launch(void* const* d_in, const int* in_sizes, int n_in,
                              void* d_out, int out_size, void* d_ws, size_t ws_size,
                              hipStream_t stream)
{
    const float* inputs = (const float*)d_in[0];
    const float* ps     = (const float*)d_in[1];
    const float* labels = (const float*)d_in[2];
    const float* rois   = (const float*)d_in[3];
    const float* fcw    = (const float*)d_in[4];
    const float* fcb    = (const float*)d_in[5];

    int B = in_sizes[2] / 4;            // 16
    int rows = B * PCNT;                // 32768
    float* out = (float*)d_out;

    char* ws = (char*)d_ws;
    size_t off = 0;
    unsigned long long* keys = (unsigned long long*)(ws + off);
    size_t keysBytes = (size_t)rows * 3 * 8;            off += keysBytes;
    off = (off + 255) & ~(size_t)255;
    float* partials = (float*)(ws + off);               off += 128 * 8 * 4;
    off = (off + 255) & ~(size_t)255;
    int* cellStart = (int*)(ws + off);                  off += (size_t)B * 64 * 4;
    int* cellCnt   = (int*)(ws + off);                  off += (size_t)B * 64 * 4;
    off = (off + 255) & ~(size_t)255;
    float4* roisE = (float4*)(ws + off);                off += (size_t)B * CAP_B * 16;
    float4* metaE = (float4*)(ws + off);                off += (size_t)B * CAP_B * 16;

    hipMemsetAsync(keys, 0, keysBytes, stream);
    k_gemv_softmax<<<rows / 16, 256, 0, stream>>>(inputs, fcw, fcb, out);
    k_bin<<<B, 1024, 0, stream>>>(rois, ps, cellStart, cellCnt, roisE, metaE);
    k_assign_cells2<<<B * 64, 512, 0, stream>>>(cellStart, cellCnt, roisE, metaE, keys);
    const int NBLK = 128;   // rows/256
    k_finalize_loss<<<NBLK, 256, 0, stream>>>(keys, ps, labels, out, partials, rows);
    k_loss_final2<<<1, 128, 0, stream>>>(partials, out + (size_t)rows * 4, NBLK, 1.f / (float)B);
}

// Round 5
// 103.736 us; speedup vs baseline: 1.2460x; 1.0613x over previous
//
#include <hip/hip_runtime.h>
#include <math.h>

#define PCNT 2048
#define CDIM 512
#define CAP_B (PCNT * 9)        // worst-case entries/batch (box spans <=3x3 cells)
#define ITEMS_B 2368            // >= CAP_B/8 + 64  (max wave-items per batch)

// ------------------------------------------------------------------
// K1: xr = inputs @ W.T + b ; logit = softmax(xr) -> out[row*4+c]
// 16 lanes per row; W staged in LDS swizzled for conflict-free b128.
// ------------------------------------------------------------------
__global__ __launch_bounds__(256) void k_gemv_softmax(
    const float* __restrict__ in, const float* __restrict__ W,
    const float* __restrict__ bias, float* __restrict__ out)
{
    __shared__ float4 w_lds[512];   // [(m*4+c)*16 + k] = W[c][k*32 + m*4 .. +3]
    int tid = threadIdx.x;
    const float4* W4 = (const float4*)W;   // [c*128 + q]
    for (int e = tid; e < 512; e += 256) {
        int m = e >> 6, rem = e & 63, c = rem >> 4, k = rem & 15;
        w_lds[e] = W4[c * 128 + k * 8 + m];
    }
    __syncthreads();
    int row = blockIdx.x * 16 + (tid >> 4);
    int k   = tid & 15;
    const float4* ip = (const float4*)(in + (size_t)row * CDIM);
    float4 v[8];
#pragma unroll
    for (int m = 0; m < 8; ++m) v[m] = ip[k * 8 + m];
    float a0 = 0.f, a1 = 0.f, a2 = 0.f, a3 = 0.f;
#pragma unroll
    for (int m = 0; m < 8; ++m) {
        float4 w0 = w_lds[(m * 4 + 0) * 16 + k];
        float4 w1 = w_lds[(m * 4 + 1) * 16 + k];
        float4 w2 = w_lds[(m * 4 + 2) * 16 + k];
        float4 w3 = w_lds[(m * 4 + 3) * 16 + k];
        a0 += v[m].x*w0.x + v[m].y*w0.y + v[m].z*w0.z + v[m].w*w0.w;
        a1 += v[m].x*w1.x + v[m].y*w1.y + v[m].z*w1.z + v[m].w*w1.w;
        a2 += v[m].x*w2.x + v[m].y*w2.y + v[m].z*w2.z + v[m].w*w2.w;
        a3 += v[m].x*w3.x + v[m].y*w3.y + v[m].z*w3.z + v[m].w*w3.w;
    }
#pragma unroll
    for (int off = 1; off < 16; off <<= 1) {
        a0 += __shfl_xor(a0, off, 64);
        a1 += __shfl_xor(a1, off, 64);
        a2 += __shfl_xor(a2, off, 64);
        a3 += __shfl_xor(a3, off, 64);
    }
    if (k == 0) {
        a0 += bias[0]; a1 += bias[1]; a2 += bias[2]; a3 += bias[3];
        float m = fmaxf(fmaxf(a0, a1), fmaxf(a2, a3));
        float e0 = expf(a0 - m), e1 = expf(a1 - m), e2 = expf(a2 - m), e3 = expf(a3 - m);
        float inv = 1.f / (e0 + e1 + e2 + e3);
        ((float4*)out)[row] = make_float4(e0 * inv, e1 * inv, e2 * inv, e3 * inv);
    }
}

// ------------------------------------------------------------------
// K2: seeds. One block per (b,c): cnt = #(sc>0.5), amax = first argmax.
// ------------------------------------------------------------------
__global__ __launch_bounds__(256) void k_seeds(
    const float* __restrict__ ps, int* __restrict__ seedsCnt,
    int* __restrict__ seedsAmax)
{
    int b = blockIdx.x / 3, c = blockIdx.x % 3;
    int tid = threadIdx.x;
    __shared__ float sval[256];
    __shared__ int   sidx[256];
    __shared__ int   scnt[256];

    float bestv = -1e30f; int besti = 0; int cnt = 0;
#pragma unroll
    for (int t = 0; t < PCNT / 256; ++t) {
        int j = tid + t * 256;
        float v = ps[((size_t)b * PCNT + j) * 4 + c];
        if (v > 0.5f) cnt++;
        if (v > bestv) { bestv = v; besti = j; }   // ascending j -> first max kept
    }
    sval[tid] = bestv; sidx[tid] = besti; scnt[tid] = cnt;
    __syncthreads();
    for (int s = 128; s > 0; s >>= 1) {
        if (tid < s) {
            float v2 = sval[tid + s]; int i2 = sidx[tid + s];
            if (v2 > sval[tid] || (v2 == sval[tid] && i2 < sidx[tid])) { sval[tid] = v2; sidx[tid] = i2; }
            scnt[tid] += scnt[tid + s];
        }
        __syncthreads();
    }
    if (tid == 0) { seedsCnt[b * 3 + c] = scnt[0]; seedsAmax[b * 3 + c] = sidx[0]; }
}

// ------------------------------------------------------------------
// K3: count boxes per (b, cell). Thread per box. cellCnt pre-zeroed.
// ------------------------------------------------------------------
__global__ __launch_bounds__(256) void k_count(
    const float* __restrict__ rois, int* __restrict__ cellCnt, int rows)
{
    int gid = blockIdx.x * 256 + threadIdx.x;
    if (gid >= rows) return;
    int b = gid >> 11;
    float4 q = ((const float4*)rois)[gid];
    int cx0 = min(((int)q.x) >> 7, 7), cx1 = min(((int)q.z) >> 7, 7);
    int cy0 = min(((int)q.y) >> 7, 7), cy1 = min(((int)q.w) >> 7, 7);
    for (int cy = cy0; cy <= cy1; ++cy)
        for (int cx = cx0; cx <= cx1; ++cx)
            atomicAdd(&cellCnt[b * 64 + cy * 8 + cx], 1);
}

// ------------------------------------------------------------------
// K4: per-batch prefix over 64 cells + build wave-item records.
// One wave per batch. item = (cell<<16)|group, group = 8 i-entries.
// ------------------------------------------------------------------
__global__ void k_scan(
    const int* __restrict__ cellCnt, int* __restrict__ cellStart,
    int* __restrict__ cellCur, int* __restrict__ itemCnt,
    unsigned* __restrict__ itemRec)
{
    int tid = threadIdx.x;
    int b = tid >> 6, lane = tid & 63;
    int cg = b * 64 + lane;
    int cnt = cellCnt[cg];
    int incl = cnt;
#pragma unroll
    for (int d = 1; d < 64; d <<= 1) {
        int v = __shfl_up(incl, d, 64);
        if (lane >= d) incl += v;
    }
    int excl = incl - cnt;
    cellStart[cg] = excl;
    cellCur[cg]   = excl;
    int grp = (cnt + 7) >> 3;
    int gincl = grp;
#pragma unroll
    for (int d = 1; d < 64; d <<= 1) {
        int v = __shfl_up(gincl, d, 64);
        if (lane >= d) gincl += v;
    }
    int gexcl = gincl - grp;
    if (lane == 63) itemCnt[b] = gincl;
    for (int g = 0; g < grp; ++g)
        itemRec[b * ITEMS_B + gexcl + g] = ((unsigned)lane << 16) | (unsigned)g;
}

// ------------------------------------------------------------------
// K5: scatter entries (box + meta(m0,m1,m2,j)) into cell lists.
// ------------------------------------------------------------------
__global__ __launch_bounds__(256) void k_scatter(
    const float* __restrict__ rois, const float* __restrict__ ps,
    const int* __restrict__ seedsCnt, const int* __restrict__ seedsAmax,
    int* __restrict__ cellCur, float4* __restrict__ roisE,
    float4* __restrict__ metaE, int rows)
{
    int gid = blockIdx.x * 256 + threadIdx.x;
    if (gid >= rows) return;
    int b = gid >> 11, j = gid & (PCNT - 1);
    float4 q  = ((const float4*)rois)[gid];
    float4 pv = ((const float4*)ps)[gid];
    float m0 = ((seedsCnt[b*3+0] <= 1) ? (j == seedsAmax[b*3+0]) : (pv.x > 0.5f)) ? 1.f : 0.f;
    float m1 = ((seedsCnt[b*3+1] <= 1) ? (j == seedsAmax[b*3+1]) : (pv.y > 0.5f)) ? 1.f : 0.f;
    float m2 = ((seedsCnt[b*3+2] <= 1) ? (j == seedsAmax[b*3+2]) : (pv.z > 0.5f)) ? 1.f : 0.f;
    float4 meta = make_float4(m0, m1, m2, __int_as_float(j));
    int cx0 = min(((int)q.x) >> 7, 7), cx1 = min(((int)q.z) >> 7, 7);
    int cy0 = min(((int)q.y) >> 7, 7), cy1 = min(((int)q.w) >> 7, 7);
    for (int cy = cy0; cy <= cy1; ++cy)
        for (int cx = cx0; cx <= cx1; ++cx) {
            int e = atomicAdd(&cellCur[b * 64 + cy * 8 + cx], 1);
            size_t pos = (size_t)b * CAP_B + e;
            roisE[pos] = q;
            metaE[pos] = meta;
        }
}

// ------------------------------------------------------------------
// K6: assignment. Wave per item: 8 i-entries x 8 j-lanes over the
// cell's entry list (L1-resident). Packed u64 key = (iou_bits<<32)|
// (0x7FFFFFFF - j) -> u64 max == (max iou, min j). Guarded atomicMax.
// ------------------------------------------------------------------
__global__ __launch_bounds__(256) void k_assign_binned(
    const int* __restrict__ cellCnt, const int* __restrict__ cellStart,
    const int* __restrict__ itemCnt, const unsigned* __restrict__ itemRec,
    const float4* __restrict__ roisE, const float4* __restrict__ metaE,
    unsigned long long* __restrict__ keys)
{
    int tid = threadIdx.x;
    int item = blockIdx.x * 4 + (tid >> 6);
    int b = item / ITEMS_B;
    int idx = item - b * ITEMS_B;
    if (idx >= itemCnt[b]) return;          // wave-uniform exit
    unsigned rec = itemRec[b * ITEMS_B + idx];
    int cell = rec >> 16, g = rec & 0xFFFF;
    int cg = b * 64 + cell;
    int n = cellCnt[cg];
    size_t base = (size_t)b * CAP_B + cellStart[cg];
    int lane = tid & 63, il = lane >> 3, jl = lane & 7;
    int ie = g * 8 + il;
    bool ivalid = ie < n;
    int iload = ivalid ? ie : 0;
    float4 r = roisE[base + iload];
    int i_prop = __float_as_int(metaE[base + iload].w);
    float areaA = (r.z - r.x) * (r.w - r.y);

    unsigned long long best0 = 0, best1 = 0, best2 = 0;
    for (int e = jl; e < n; e += 8) {
        float4 q = roisE[base + e];
        float4 m = metaE[base + e];
        float lx = fmaxf(r.x, q.x), ly = fmaxf(r.y, q.y);
        float rx = fminf(r.z, q.z), ry = fminf(r.w, q.w);
        float ww = fmaxf(rx - lx, 0.f);
        float hh = fmaxf(ry - ly, 0.f);
        float inter = ww * hh;
        float areaB = (q.z - q.x) * (q.w - q.y);
        float u = (areaA + areaB) - inter;
        float ioup1 = fmaf(inter, __builtin_amdgcn_rcpf(u), 1.0f);   // iou+1
        unsigned lo = 0x7FFFFFFFu - (unsigned)__float_as_int(m.w);
        float t0 = fmaxf(fmaf(ioup1, m.x, -1.0f), 0.f);   // seed? iou : 0 (clamped)
        float t1 = fmaxf(fmaf(ioup1, m.y, -1.0f), 0.f);
        float t2 = fmaxf(fmaf(ioup1, m.z, -1.0f), 0.f);
        unsigned long long k0 = ((unsigned long long)(unsigned)__float_as_int(t0) << 32) | lo;
        unsigned long long k1 = ((unsigned long long)(unsigned)__float_as_int(t1) << 32) | lo;
        unsigned long long k2 = ((unsigned long long)(unsigned)__float_as_int(t2) << 32) | lo;
        if (k0 > best0) best0 = k0;
        if (k1 > best1) best1 = k1;
        if (k2 > best2) best2 = k2;
    }
#pragma unroll
    for (int off = 1; off < 8; off <<= 1) {
        unsigned long long o;
        o = __shfl_xor(best0, off, 64); if (o > best0) best0 = o;
        o = __shfl_xor(best1, off, 64); if (o > best1) best1 = o;
        o = __shfl_xor(best2, off, 64); if (o > best2) best2 = o;
    }
    if (jl == 0 && ivalid) {
        size_t kb = ((size_t)b * PCNT + i_prop) * 3;
        if ((unsigned)(best0 >> 32) >= 0x3F000000u) atomicMax(&keys[kb + 0], best0);
        if ((unsigned)(best1 >> 32) >= 0x3F000000u) atomicMax(&keys[kb + 1], best1);
        if ((unsigned)(best2 >> 32) >= 0x3F000000u) atomicMax(&keys[kb + 2], best2);
    }
}

// ------------------------------------------------------------------
// K6-fallback (ws too small): full scan, wave per 8 i's, same keys.
// ------------------------------------------------------------------
__global__ __launch_bounds__(256) void k_assign_fallback(
    const float* __restrict__ rois, const float* __restrict__ ps,
    const int* __restrict__ seedsCnt, const int* __restrict__ seedsAmax,
    unsigned long long* __restrict__ keys)
{
    int tid = threadIdx.x;
    int item = blockIdx.x * 4 + (tid >> 6);
    int b = item >> 8;                 // 256 items per batch
    int g = item & 255;
    int lane = tid & 63, il = lane >> 3, jl = lane & 7;
    int ie = g * 8 + il;
    const float4* rb = (const float4*)rois + (size_t)b * PCNT;
    const float4* pb = (const float4*)ps + (size_t)b * PCNT;
    float4 r = rb[ie];
    float areaA = (r.z - r.x) * (r.w - r.y);
    int c0 = seedsCnt[b*3+0], a0 = seedsAmax[b*3+0];
    int c1 = seedsCnt[b*3+1], a1 = seedsAmax[b*3+1];
    int c2 = seedsCnt[b*3+2], a2 = seedsAmax[b*3+2];

    unsigned long long best0 = 0, best1 = 0, best2 = 0;
    for (int e = jl; e < PCNT; e += 8) {
        float4 q = rb[e];
        float4 pv = pb[e];
        float m0 = ((c0 <= 1) ? (e == a0) : (pv.x > 0.5f)) ? 1.f : 0.f;
        float m1 = ((c1 <= 1) ? (e == a1) : (pv.y > 0.5f)) ? 1.f : 0.f;
        float m2 = ((c2 <= 1) ? (e == a2) : (pv.z > 0.5f)) ? 1.f : 0.f;
        float lx = fmaxf(r.x, q.x), ly = fmaxf(r.y, q.y);
        float rx = fminf(r.z, q.z), ry = fminf(r.w, q.w);
        float ww = fmaxf(rx - lx, 0.f);
        float hh = fmaxf(ry - ly, 0.f);
        float inter = ww * hh;
        float areaB = (q.z - q.x) * (q.w - q.y);
        float u = (areaA + areaB) - inter;
        float ioup1 = fmaf(inter, __builtin_amdgcn_rcpf(u), 1.0f);
        unsigned lo = 0x7FFFFFFFu - (unsigned)e;
        float t0 = fmaxf(fmaf(ioup1, m0, -1.0f), 0.f);
        float t1 = fmaxf(fmaf(ioup1, m1, -1.0f), 0.f);
        float t2 = fmaxf(fmaf(ioup1, m2, -1.0f), 0.f);
        unsigned long long k0 = ((unsigned long long)(unsigned)__float_as_int(t0) << 32) | lo;
        unsigned long long k1 = ((unsigned long long)(unsigned)__float_as_int(t1) << 32) | lo;
        unsigned long long k2 = ((unsigned long long)(unsigned)__float_as_int(t2) << 32) | lo;
        if (k0 > best0) best0 = k0;
        if (k1 > best1) best1 = k1;
        if (k2 > best2) best2 = k2;
    }
#pragma unroll
    for (int off = 1; off < 8; off <<= 1) {
        unsigned long long o;
        o = __shfl_xor(best0, off, 64); if (o > best0) best0 = o;
        o = __shfl_xor(best1, off, 64); if (o > best1) best1 = o;
        o = __shfl_xor(best2, off, 64); if (o > best2) best2 = o;
    }
    if (jl == 0) {
        size_t kb = ((size_t)b * PCNT + ie) * 3;
        if ((unsigned)(best0 >> 32) >= 0x3F000000u) atomicMax(&keys[kb + 0], best0);
        if ((unsigned)(best1 >> 32) >= 0x3F000000u) atomicMax(&keys[kb + 1], best1);
        if ((unsigned)(best2 >> 32) >= 0x3F000000u) atomicMax(&keys[kb + 2], best2);
    }
}

// ------------------------------------------------------------------
// K7: finalize assignment + per-class partial loss sums/counts.
// ------------------------------------------------------------------
__global__ __launch_bounds__(256) void k_finalize_loss(
    const unsigned long long* __restrict__ keys, const float* __restrict__ ps,
    const float* __restrict__ labels, const float* __restrict__ logit,
    float* __restrict__ partials, int rows)
{
    int tid = threadIdx.x;
    int row = blockIdx.x * 256 + tid;
    float s0 = 0.f, s1 = 0.f, s2 = 0.f, s3 = 0.f;
    float c0 = 0.f, c1 = 0.f, c2 = 0.f, c3 = 0.f;
    if (row < rows) {
        int b = row >> 11;
        float I = -1.f; int cls = 3; float wv = 1.f;
#pragma unroll
        for (int c = 0; c < 3; ++c) {
            unsigned long long key = keys[(size_t)row * 3 + c];
            float lab = labels[b * 4 + c];
            if (key != 0ull && lab > 0.f) {
                float t = __uint_as_float((unsigned)(key >> 32));
                if (t >= 0.5f && t > I) {
                    int j = 0x7FFFFFFF - (int)(key & 0xFFFFFFFFull);
                    I = t; cls = c;
                    wv = ps[((size_t)b * PCNT + j) * 4 + c];
                }
            }
        }
        float4 lg = ((const float4*)logit)[row];
        float l = (cls == 0) ? lg.x : (cls == 1) ? lg.y : (cls == 2) ? lg.z : lg.w;
        float p = fminf(fmaxf(l, 1e-7f), 1.f - 1e-7f);
        float om = 1.f - p;
        float fl = -logf(p) * om * om;
        float lab = (cls == 3) ? 1.f : labels[b * 4 + cls];
        float wu = 10.f * expf(l) * (1.f - lab) + lab;
        float contrib = wv * fl * wu;
        s0 = (cls == 0) ? contrib : 0.f; c0 = (cls == 0) ? 1.f : 0.f;
        s1 = (cls == 1) ? contrib : 0.f; c1 = (cls == 1) ? 1.f : 0.f;
        s2 = (cls == 2) ? contrib : 0.f; c2 = (cls == 2) ? 1.f : 0.f;
        s3 = (cls == 3) ? contrib : 0.f; c3 = (cls == 3) ? 1.f : 0.f;
    }
    __shared__ float red[256];
    float vals[8] = {s0, s1, s2, s3, c0, c1, c2, c3};
#pragma unroll
    for (int comp = 0; comp < 8; ++comp) {
        red[tid] = vals[comp];
        __syncthreads();
        for (int s = 128; s > 0; s >>= 1) {
            if (tid < s) red[tid] += red[tid + s];
            __syncthreads();
        }
        if (tid == 0) partials[blockIdx.x * 8 + comp] = red[0];
        __syncthreads();
    }
}

// ------------------------------------------------------------------
// K8: final reduce: loss = sum_c S_c / (N_c + 1e-7) / B
// ------------------------------------------------------------------
__global__ __launch_bounds__(128) void k_loss_final2(
    const float* __restrict__ partials, float* __restrict__ out_loss,
    int nblk, float invB)
{
    int tid = threadIdx.x;
    __shared__ float red[128];
    float acc[8];
#pragma unroll
    for (int comp = 0; comp < 8; ++comp) {
        red[tid] = (tid < nblk) ? partials[tid * 8 + comp] : 0.f;
        __syncthreads();
        for (int s = 64; s > 0; s >>= 1) {
            if (tid < s) red[tid] += red[tid + s];
            __syncthreads();
        }
        acc[comp] = red[0];
        __syncthreads();
    }
    if (tid == 0) {
        float loss = 0.f;
#pragma unroll
        for (int c = 0; c < 4; ++c) loss += acc[c] / (acc[4 + c] + 1e-7f);
        *out_loss = loss * invB;
    }
}

extern "C" void kernel_launch(void* const* d_in, const int* in_sizes, int n_in,
                              void* d_out, int out_size, void* d_ws, size_t ws_size,
                              hipStream_t stream)
{
    const float* inputs = (const float*)d_in[0];
    const float* ps     = (const float*)d_in[1];
    const float* labels = (const float*)d_in[2];
    const float* rois   = (const float*)d_in[3];
    const float* fcw    = (const float*)d_in[4];
    const float* fcb    = (const float*)d_in[5];

    int B = in_sizes[2] / 4;            // 16
    int rows = B * PCNT;                // 32768
    float* out = (float*)d_out;

    char* ws = (char*)d_ws;
    size_t off = 0;
    unsigned long long* keys = (unsigned long long*)(ws + off);
    size_t keysBytes = (size_t)rows * 3 * 8;            off += keysBytes;
    off = (off + 255) & ~(size_t)255;
    float* partials = (float*)(ws + off);               off += 128 * 8 * 4;
    int* seedsCnt  = (int*)(ws + off);                  off += (size_t)B * 3 * 4;
    int* seedsAmax = (int*)(ws + off);                  off += (size_t)B * 3 * 4;
    off = (off + 255) & ~(size_t)255;
    size_t smallEnd = off;
    int* cellCnt   = (int*)(ws + off);                  off += (size_t)B * 64 * 4;
    int* cellStart = (int*)(ws + off);                  off += (size_t)B * 64 * 4;
    int* cellCur   = (int*)(ws + off);                  off += (size_t)B * 64 * 4;
    int* itemCnt   = (int*)(ws + off);                  off += (size_t)B * 4;
    off = (off + 255) & ~(size_t)255;
    unsigned* itemRec = (unsigned*)(ws + off);          off += (size_t)B * ITEMS_B * 4;
    off = (off + 255) & ~(size_t)255;
    float4* roisE = (float4*)(ws + off);                off += (size_t)B * CAP_B * 16;
    float4* metaE = (float4*)(ws + off);                off += (size_t)B * CAP_B * 16;
    bool binned = (ws_size >= off);

    hipMemsetAsync(keys, 0, keysBytes, stream);
    k_gemv_softmax<<<rows / 16, 256, 0, stream>>>(inputs, fcw, fcb, out);
    k_seeds<<<B * 3, 256, 0, stream>>>(ps, seedsCnt, seedsAmax);
    if (binned) {
        hipMemsetAsync(cellCnt, 0, (size_t)B * 64 * 4, stream);
        k_count<<<rows / 256, 256, 0, stream>>>(rois, cellCnt, rows);
        k_scan<<<1, B * 64, 0, stream>>>(cellCnt, cellStart, cellCur, itemCnt, itemRec);
        k_scatter<<<rows / 256, 256, 0, stream>>>(rois, ps, seedsCnt, seedsAmax,
                                                  cellCur, roisE, metaE, rows);
        k_assign_binned<<<B * (ITEMS_B / 4), 256, 0, stream>>>(
            cellCnt, cellStart, itemCnt, itemRec, roisE, metaE, keys);
    } else {
        (void)smallEnd;
        k_assign_fallback<<<B * 64, 256, 0, stream>>>(rois, ps, seedsCnt, seedsAmax, keys);
    }
    const int NBLK = 128;   // rows/256
    k_finalize_loss<<<NBLK, 256, 0, stream>>>(keys, ps, labels, out, partials, rows);
    k_loss_final2<<<1, 128, 0, stream>>>(partials, out + (size_t)rows * 4, NBLK, 1.f / (float)B);
}

// Round 6
// 94.136 us; speedup vs baseline: 1.3730x; 1.1020x over previous
//
#include <hip/hip_runtime.h>
#include <math.h>

#define PCNT 2048
#define CDIM 512
#define CAP_B (PCNT * 9)        // worst-case entries/batch (box spans <=3x3 cells)
#define ITEMS_B 2368            // >= CAP_B/8 + 64  (max wave-items per batch)

// ------------------------------------------------------------------
// K1: xr = inputs @ W.T + b ; logit = softmax(xr) -> out[row*4+c]
// 16 lanes per row; W staged in LDS swizzled for conflict-free b128.
// Also zero-fills keys[] and cellCnt[] (replaces slow hipMemsetAsync:
// graph-captured fillBuffer was ~39us each at 8% occupancy).
// ------------------------------------------------------------------
__global__ __launch_bounds__(256) void k_gemv_softmax(
    const float* __restrict__ in, const float* __restrict__ W,
    const float* __restrict__ bias, float* __restrict__ out,
    unsigned long long* __restrict__ keys, int nkeys,
    int* __restrict__ cellCnt, int ncell)
{
    __shared__ float4 w_lds[512];   // [(m*4+c)*16 + k] = W[c][k*32 + m*4 .. +3]
    int tid = threadIdx.x;
    int gid = blockIdx.x * 256 + tid;
    if (gid < nkeys) keys[gid] = 0ull;
    if (gid < ncell) cellCnt[gid] = 0;
    const float4* W4 = (const float4*)W;   // [c*128 + q]
    for (int e = tid; e < 512; e += 256) {
        int m = e >> 6, rem = e & 63, c = rem >> 4, k = rem & 15;
        w_lds[e] = W4[c * 128 + k * 8 + m];
    }
    __syncthreads();
    int row = blockIdx.x * 16 + (tid >> 4);
    int k   = tid & 15;
    const float4* ip = (const float4*)(in + (size_t)row * CDIM);
    float4 v[8];
#pragma unroll
    for (int m = 0; m < 8; ++m) v[m] = ip[k * 8 + m];
    float a0 = 0.f, a1 = 0.f, a2 = 0.f, a3 = 0.f;
#pragma unroll
    for (int m = 0; m < 8; ++m) {
        float4 w0 = w_lds[(m * 4 + 0) * 16 + k];
        float4 w1 = w_lds[(m * 4 + 1) * 16 + k];
        float4 w2 = w_lds[(m * 4 + 2) * 16 + k];
        float4 w3 = w_lds[(m * 4 + 3) * 16 + k];
        a0 += v[m].x*w0.x + v[m].y*w0.y + v[m].z*w0.z + v[m].w*w0.w;
        a1 += v[m].x*w1.x + v[m].y*w1.y + v[m].z*w1.z + v[m].w*w1.w;
        a2 += v[m].x*w2.x + v[m].y*w2.y + v[m].z*w2.z + v[m].w*w2.w;
        a3 += v[m].x*w3.x + v[m].y*w3.y + v[m].z*w3.z + v[m].w*w3.w;
    }
#pragma unroll
    for (int off = 1; off < 16; off <<= 1) {
        a0 += __shfl_xor(a0, off, 64);
        a1 += __shfl_xor(a1, off, 64);
        a2 += __shfl_xor(a2, off, 64);
        a3 += __shfl_xor(a3, off, 64);
    }
    if (k == 0) {
        a0 += bias[0]; a1 += bias[1]; a2 += bias[2]; a3 += bias[3];
        float m = fmaxf(fmaxf(a0, a1), fmaxf(a2, a3));
        float e0 = expf(a0 - m), e1 = expf(a1 - m), e2 = expf(a2 - m), e3 = expf(a3 - m);
        float inv = 1.f / (e0 + e1 + e2 + e3);
        ((float4*)out)[row] = make_float4(e0 * inv, e1 * inv, e2 * inv, e3 * inv);
    }
}

// ------------------------------------------------------------------
// K2: fused seeds + cell-count. Blocks [0, seedBlocks) do the per-(b,c)
// seed stats; remaining blocks count boxes per (b, cell).
// ------------------------------------------------------------------
__global__ __launch_bounds__(256) void k_seeds_count(
    const float* __restrict__ ps, int* __restrict__ seedsCnt,
    int* __restrict__ seedsAmax, const float* __restrict__ rois,
    int* __restrict__ cellCnt, int rows, int seedBlocks)
{
    int tid = threadIdx.x;
    if (blockIdx.x < (unsigned)seedBlocks) {
        int b = blockIdx.x / 3, c = blockIdx.x % 3;
        __shared__ float sval[256];
        __shared__ int   sidx[256];
        __shared__ int   scnt[256];
        float bestv = -1e30f; int besti = 0; int cnt = 0;
#pragma unroll
        for (int t = 0; t < PCNT / 256; ++t) {
            int j = tid + t * 256;
            float v = ps[((size_t)b * PCNT + j) * 4 + c];
            if (v > 0.5f) cnt++;
            if (v > bestv) { bestv = v; besti = j; }   // ascending j -> first max kept
        }
        sval[tid] = bestv; sidx[tid] = besti; scnt[tid] = cnt;
        __syncthreads();
        for (int s = 128; s > 0; s >>= 1) {
            if (tid < s) {
                float v2 = sval[tid + s]; int i2 = sidx[tid + s];
                if (v2 > sval[tid] || (v2 == sval[tid] && i2 < sidx[tid])) { sval[tid] = v2; sidx[tid] = i2; }
                scnt[tid] += scnt[tid + s];
            }
            __syncthreads();
        }
        if (tid == 0) { seedsCnt[b * 3 + c] = scnt[0]; seedsAmax[b * 3 + c] = sidx[0]; }
    } else {
        int gid = (blockIdx.x - seedBlocks) * 256 + tid;
        if (gid >= rows) return;
        int b = gid >> 11;
        float4 q = ((const float4*)rois)[gid];
        int cx0 = min(((int)q.x) >> 7, 7), cx1 = min(((int)q.z) >> 7, 7);
        int cy0 = min(((int)q.y) >> 7, 7), cy1 = min(((int)q.w) >> 7, 7);
        for (int cy = cy0; cy <= cy1; ++cy)
            for (int cx = cx0; cx <= cx1; ++cx)
                atomicAdd(&cellCnt[b * 64 + cy * 8 + cx], 1);
    }
}

// ------------------------------------------------------------------
// K3: per-batch prefix over 64 cells + build wave-item records.
// One wave per batch. item = (cell<<16)|group, group = 8 i-entries.
// ------------------------------------------------------------------
__global__ void k_scan(
    const int* __restrict__ cellCnt, int* __restrict__ cellStart,
    int* __restrict__ cellCur, int* __restrict__ itemCnt,
    unsigned* __restrict__ itemRec)
{
    int tid = threadIdx.x;
    int b = tid >> 6, lane = tid & 63;
    int cg = b * 64 + lane;
    int cnt = cellCnt[cg];
    int incl = cnt;
#pragma unroll
    for (int d = 1; d < 64; d <<= 1) {
        int v = __shfl_up(incl, d, 64);
        if (lane >= d) incl += v;
    }
    int excl = incl - cnt;
    cellStart[cg] = excl;
    cellCur[cg]   = excl;
    int grp = (cnt + 7) >> 3;
    int gincl = grp;
#pragma unroll
    for (int d = 1; d < 64; d <<= 1) {
        int v = __shfl_up(gincl, d, 64);
        if (lane >= d) gincl += v;
    }
    int gexcl = gincl - grp;
    if (lane == 63) itemCnt[b] = gincl;
    for (int g = 0; g < grp; ++g)
        itemRec[b * ITEMS_B + gexcl + g] = ((unsigned)lane << 16) | (unsigned)g;
}

// ------------------------------------------------------------------
// K4: scatter entries (box + meta(m0,m1,m2,j)) into cell lists.
// ------------------------------------------------------------------
__global__ __launch_bounds__(256) void k_scatter(
    const float* __restrict__ rois, const float* __restrict__ ps,
    const int* __restrict__ seedsCnt, const int* __restrict__ seedsAmax,
    int* __restrict__ cellCur, float4* __restrict__ roisE,
    float4* __restrict__ metaE, int rows)
{
    int gid = blockIdx.x * 256 + threadIdx.x;
    if (gid >= rows) return;
    int b = gid >> 11, j = gid & (PCNT - 1);
    float4 q  = ((const float4*)rois)[gid];
    float4 pv = ((const float4*)ps)[gid];
    float m0 = ((seedsCnt[b*3+0] <= 1) ? (j == seedsAmax[b*3+0]) : (pv.x > 0.5f)) ? 1.f : 0.f;
    float m1 = ((seedsCnt[b*3+1] <= 1) ? (j == seedsAmax[b*3+1]) : (pv.y > 0.5f)) ? 1.f : 0.f;
    float m2 = ((seedsCnt[b*3+2] <= 1) ? (j == seedsAmax[b*3+2]) : (pv.z > 0.5f)) ? 1.f : 0.f;
    float4 meta = make_float4(m0, m1, m2, __int_as_float(j));
    int cx0 = min(((int)q.x) >> 7, 7), cx1 = min(((int)q.z) >> 7, 7);
    int cy0 = min(((int)q.y) >> 7, 7), cy1 = min(((int)q.w) >> 7, 7);
    for (int cy = cy0; cy <= cy1; ++cy)
        for (int cx = cx0; cx <= cx1; ++cx) {
            int e = atomicAdd(&cellCur[b * 64 + cy * 8 + cx], 1);
            size_t pos = (size_t)b * CAP_B + e;
            roisE[pos] = q;
            metaE[pos] = meta;
        }
}

// ------------------------------------------------------------------
// K5: assignment. Wave per item: 8 i-entries x 8 j-lanes over the
// cell's entry list (L1-resident). Packed u64 key = (iou_bits<<32)|
// (0x7FFFFFFF - j) -> u64 max == (max iou, min j). Guarded atomicMax.
// ------------------------------------------------------------------
__global__ __launch_bounds__(256) void k_assign_binned(
    const int* __restrict__ cellCnt, const int* __restrict__ cellStart,
    const int* __restrict__ itemCnt, const unsigned* __restrict__ itemRec,
    const float4* __restrict__ roisE, const float4* __restrict__ metaE,
    unsigned long long* __restrict__ keys)
{
    int tid = threadIdx.x;
    int item = blockIdx.x * 4 + (tid >> 6);
    int b = item / ITEMS_B;
    int idx = item - b * ITEMS_B;
    if (idx >= itemCnt[b]) return;          // wave-uniform exit
    unsigned rec = itemRec[b * ITEMS_B + idx];
    int cell = rec >> 16, g = rec & 0xFFFF;
    int cg = b * 64 + cell;
    int n = cellCnt[cg];
    size_t base = (size_t)b * CAP_B + cellStart[cg];
    int lane = tid & 63, il = lane >> 3, jl = lane & 7;
    int ie = g * 8 + il;
    bool ivalid = ie < n;
    int iload = ivalid ? ie : 0;
    float4 r = roisE[base + iload];
    int i_prop = __float_as_int(metaE[base + iload].w);
    float areaA = (r.z - r.x) * (r.w - r.y);

    unsigned long long best0 = 0, best1 = 0, best2 = 0;
    for (int e = jl; e < n; e += 8) {
        float4 q = roisE[base + e];
        float4 m = metaE[base + e];
        float lx = fmaxf(r.x, q.x), ly = fmaxf(r.y, q.y);
        float rx = fminf(r.z, q.z), ry = fminf(r.w, q.w);
        float ww = fmaxf(rx - lx, 0.f);
        float hh = fmaxf(ry - ly, 0.f);
        float inter = ww * hh;
        float areaB = (q.z - q.x) * (q.w - q.y);
        float u = (areaA + areaB) - inter;
        float ioup1 = fmaf(inter, __builtin_amdgcn_rcpf(u), 1.0f);   // iou+1
        unsigned lo = 0x7FFFFFFFu - (unsigned)__float_as_int(m.w);
        float t0 = fmaxf(fmaf(ioup1, m.x, -1.0f), 0.f);   // seed? iou : 0 (clamped)
        float t1 = fmaxf(fmaf(ioup1, m.y, -1.0f), 0.f);
        float t2 = fmaxf(fmaf(ioup1, m.z, -1.0f), 0.f);
        unsigned long long k0 = ((unsigned long long)(unsigned)__float_as_int(t0) << 32) | lo;
        unsigned long long k1 = ((unsigned long long)(unsigned)__float_as_int(t1) << 32) | lo;
        unsigned long long k2 = ((unsigned long long)(unsigned)__float_as_int(t2) << 32) | lo;
        if (k0 > best0) best0 = k0;
        if (k1 > best1) best1 = k1;
        if (k2 > best2) best2 = k2;
    }
#pragma unroll
    for (int off = 1; off < 8; off <<= 1) {
        unsigned long long o;
        o = __shfl_xor(best0, off, 64); if (o > best0) best0 = o;
        o = __shfl_xor(best1, off, 64); if (o > best1) best1 = o;
        o = __shfl_xor(best2, off, 64); if (o > best2) best2 = o;
    }
    if (jl == 0 && ivalid) {
        size_t kb = ((size_t)b * PCNT + i_prop) * 3;
        if ((unsigned)(best0 >> 32) >= 0x3F000000u) atomicMax(&keys[kb + 0], best0);
        if ((unsigned)(best1 >> 32) >= 0x3F000000u) atomicMax(&keys[kb + 1], best1);
        if ((unsigned)(best2 >> 32) >= 0x3F000000u) atomicMax(&keys[kb + 2], best2);
    }
}

// ------------------------------------------------------------------
// K5-fallback (ws too small): full scan, wave per 8 i's, same keys.
// ------------------------------------------------------------------
__global__ __launch_bounds__(256) void k_assign_fallback(
    const float* __restrict__ rois, const float* __restrict__ ps,
    const int* __restrict__ seedsCnt, const int* __restrict__ seedsAmax,
    unsigned long long* __restrict__ keys)
{
    int tid = threadIdx.x;
    int item = blockIdx.x * 4 + (tid >> 6);
    int b = item >> 8;                 // 256 items per batch
    int g = item & 255;
    int lane = tid & 63, il = lane >> 3, jl = lane & 7;
    int ie = g * 8 + il;
    const float4* rb = (const float4*)rois + (size_t)b * PCNT;
    const float4* pb = (const float4*)ps + (size_t)b * PCNT;
    float4 r = rb[ie];
    float areaA = (r.z - r.x) * (r.w - r.y);
    int c0 = seedsCnt[b*3+0], a0 = seedsAmax[b*3+0];
    int c1 = seedsCnt[b*3+1], a1 = seedsAmax[b*3+1];
    int c2 = seedsCnt[b*3+2], a2 = seedsAmax[b*3+2];

    unsigned long long best0 = 0, best1 = 0, best2 = 0;
    for (int e = jl; e < PCNT; e += 8) {
        float4 q = rb[e];
        float4 pv = pb[e];
        float m0 = ((c0 <= 1) ? (e == a0) : (pv.x > 0.5f)) ? 1.f : 0.f;
        float m1 = ((c1 <= 1) ? (e == a1) : (pv.y > 0.5f)) ? 1.f : 0.f;
        float m2 = ((c2 <= 1) ? (e == a2) : (pv.z > 0.5f)) ? 1.f : 0.f;
        float lx = fmaxf(r.x, q.x), ly = fmaxf(r.y, q.y);
        float rx = fminf(r.z, q.z), ry = fminf(r.w, q.w);
        float ww = fmaxf(rx - lx, 0.f);
        float hh = fmaxf(ry - ly, 0.f);
        float inter = ww * hh;
        float areaB = (q.z - q.x) * (q.w - q.y);
        float u = (areaA + areaB) - inter;
        float ioup1 = fmaf(inter, __builtin_amdgcn_rcpf(u), 1.0f);
        unsigned lo = 0x7FFFFFFFu - (unsigned)e;
        float t0 = fmaxf(fmaf(ioup1, m0, -1.0f), 0.f);
        float t1 = fmaxf(fmaf(ioup1, m1, -1.0f), 0.f);
        float t2 = fmaxf(fmaf(ioup1, m2, -1.0f), 0.f);
        unsigned long long k0 = ((unsigned long long)(unsigned)__float_as_int(t0) << 32) | lo;
        unsigned long long k1 = ((unsigned long long)(unsigned)__float_as_int(t1) << 32) | lo;
        unsigned long long k2 = ((unsigned long long)(unsigned)__float_as_int(t2) << 32) | lo;
        if (k0 > best0) best0 = k0;
        if (k1 > best1) best1 = k1;
        if (k2 > best2) best2 = k2;
    }
#pragma unroll
    for (int off = 1; off < 8; off <<= 1) {
        unsigned long long o;
        o = __shfl_xor(best0, off, 64); if (o > best0) best0 = o;
        o = __shfl_xor(best1, off, 64); if (o > best1) best1 = o;
        o = __shfl_xor(best2, off, 64); if (o > best2) best2 = o;
    }
    if (jl == 0) {
        size_t kb = ((size_t)b * PCNT + ie) * 3;
        if ((unsigned)(best0 >> 32) >= 0x3F000000u) atomicMax(&keys[kb + 0], best0);
        if ((unsigned)(best1 >> 32) >= 0x3F000000u) atomicMax(&keys[kb + 1], best1);
        if ((unsigned)(best2 >> 32) >= 0x3F000000u) atomicMax(&keys[kb + 2], best2);
    }
}

// ------------------------------------------------------------------
// K6: finalize assignment + per-class partial loss sums/counts.
// ------------------------------------------------------------------
__global__ __launch_bounds__(256) void k_finalize_loss(
    const unsigned long long* __restrict__ keys, const float* __restrict__ ps,
    const float* __restrict__ labels, const float* __restrict__ logit,
    float* __restrict__ partials, int rows)
{
    int tid = threadIdx.x;
    int row = blockIdx.x * 256 + tid;
    float s0 = 0.f, s1 = 0.f, s2 = 0.f, s3 = 0.f;
    float c0 = 0.f, c1 = 0.f, c2 = 0.f, c3 = 0.f;
    if (row < rows) {
        int b = row >> 11;
        float I = -1.f; int cls = 3; float wv = 1.f;
#pragma unroll
        for (int c = 0; c < 3; ++c) {
            unsigned long long key = keys[(size_t)row * 3 + c];
            float lab = labels[b * 4 + c];
            if (key != 0ull && lab > 0.f) {
                float t = __uint_as_float((unsigned)(key >> 32));
                if (t >= 0.5f && t > I) {
                    int j = 0x7FFFFFFF - (int)(key & 0xFFFFFFFFull);
                    I = t; cls = c;
                    wv = ps[((size_t)b * PCNT + j) * 4 + c];
                }
            }
        }
        float4 lg = ((const float4*)logit)[row];
        float l = (cls == 0) ? lg.x : (cls == 1) ? lg.y : (cls == 2) ? lg.z : lg.w;
        float p = fminf(fmaxf(l, 1e-7f), 1.f - 1e-7f);
        float om = 1.f - p;
        float fl = -logf(p) * om * om;
        float lab = (cls == 3) ? 1.f : labels[b * 4 + cls];
        float wu = 10.f * expf(l) * (1.f - lab) + lab;
        float contrib = wv * fl * wu;
        s0 = (cls == 0) ? contrib : 0.f; c0 = (cls == 0) ? 1.f : 0.f;
        s1 = (cls == 1) ? contrib : 0.f; c1 = (cls == 1) ? 1.f : 0.f;
        s2 = (cls == 2) ? contrib : 0.f; c2 = (cls == 2) ? 1.f : 0.f;
        s3 = (cls == 3) ? contrib : 0.f; c3 = (cls == 3) ? 1.f : 0.f;
    }
    __shared__ float red[256];
    float vals[8] = {s0, s1, s2, s3, c0, c1, c2, c3};
#pragma unroll
    for (int comp = 0; comp < 8; ++comp) {
        red[tid] = vals[comp];
        __syncthreads();
        for (int s = 128; s > 0; s >>= 1) {
            if (tid < s) red[tid] += red[tid + s];
            __syncthreads();
        }
        if (tid == 0) partials[blockIdx.x * 8 + comp] = red[0];
        __syncthreads();
    }
}

// ------------------------------------------------------------------
// K7: final reduce: loss = sum_c S_c / (N_c + 1e-7) / B
// ------------------------------------------------------------------
__global__ __launch_bounds__(128) void k_loss_final2(
    const float* __restrict__ partials, float* __restrict__ out_loss,
    int nblk, float invB)
{
    int tid = threadIdx.x;
    __shared__ float red[128];
    float acc[8];
#pragma unroll
    for (int comp = 0; comp < 8; ++comp) {
        red[tid] = (tid < nblk) ? partials[tid * 8 + comp] : 0.f;
        __syncthreads();
        for (int s = 64; s > 0; s >>= 1) {
            if (tid < s) red[tid] += red[tid + s];
            __syncthreads();
        }
        acc[comp] = red[0];
        __syncthreads();
    }
    if (tid == 0) {
        float loss = 0.f;
#pragma unroll
        for (int c = 0; c < 4; ++c) loss += acc[c] / (acc[4 + c] + 1e-7f);
        *out_loss = loss * invB;
    }
}

extern "C" void kernel_launch(void* const* d_in, const int* in_sizes, int n_in,
                              void* d_out, int out_size, void* d_ws, size_t ws_size,
                              hipStream_t stream)
{
    const float* inputs = (const float*)d_in[0];
    const float* ps     = (const float*)d_in[1];
    const float* labels = (const float*)d_in[2];
    const float* rois   = (const float*)d_in[3];
    const float* fcw    = (const float*)d_in[4];
    const float* fcb    = (const float*)d_in[5];

    int B = in_sizes[2] / 4;            // 16
    int rows = B * PCNT;                // 32768
    float* out = (float*)d_out;

    char* ws = (char*)d_ws;
    size_t off = 0;
    unsigned long long* keys = (unsigned long long*)(ws + off);
    int nkeys = rows * 3;
    off += (size_t)nkeys * 8;
    off = (off + 255) & ~(size_t)255;
    float* partials = (float*)(ws + off);               off += 128 * 8 * 4;
    int* seedsCnt  = (int*)(ws + off);                  off += (size_t)B * 3 * 4;
    int* seedsAmax = (int*)(ws + off);                  off += (size_t)B * 3 * 4;
    off = (off + 255) & ~(size_t)255;
    int* cellCnt   = (int*)(ws + off);                  off += (size_t)B * 64 * 4;
    int* cellStart = (int*)(ws + off);                  off += (size_t)B * 64 * 4;
    int* cellCur   = (int*)(ws + off);                  off += (size_t)B * 64 * 4;
    int* itemCnt   = (int*)(ws + off);                  off += (size_t)B * 4;
    off = (off + 255) & ~(size_t)255;
    unsigned* itemRec = (unsigned*)(ws + off);          off += (size_t)B * ITEMS_B * 4;
    off = (off + 255) & ~(size_t)255;
    float4* roisE = (float4*)(ws + off);                off += (size_t)B * CAP_B * 16;
    float4* metaE = (float4*)(ws + off);                off += (size_t)B * CAP_B * 16;
    bool binned = (ws_size >= off);

    k_gemv_softmax<<<rows / 16, 256, 0, stream>>>(inputs, fcw, fcb, out,
                                                  keys, nkeys, cellCnt, B * 64);
    if (binned) {
        int seedBlocks = B * 3;
        k_seeds_count<<<seedBlocks + rows / 256, 256, 0, stream>>>(
            ps, seedsCnt, seedsAmax, rois, cellCnt, rows, seedBlocks);
        k_scan<<<1, B * 64, 0, stream>>>(cellCnt, cellStart, cellCur, itemCnt, itemRec);
        k_scatter<<<rows / 256, 256, 0, stream>>>(rois, ps, seedsCnt, seedsAmax,
                                                  cellCur, roisE, metaE, rows);
        k_assign_binned<<<B * (ITEMS_B / 4), 256, 0, stream>>>(
            cellCnt, cellStart, itemCnt, itemRec, roisE, metaE, keys);
    } else {
        k_seeds_count<<<B * 3, 256, 0, stream>>>(
            ps, seedsCnt, seedsAmax, rois, cellCnt, rows, B * 3);
        k_assign_fallback<<<B * 64, 256, 0, stream>>>(rois, ps, seedsCnt, seedsAmax, keys);
    }
    const int NBLK = 128;   // rows/256
    k_finalize_loss<<<NBLK, 256, 0, stream>>>(keys, ps, labels, out, partials, rows);
    k_loss_final2<<<1, 128, 0, stream>>>(partials, out + (size_t)rows * 4, NBLK, 1.f / (float)B);
}

// Round 7
// 76.882 us; speedup vs baseline: 1.6812x; 1.2244x over previous
//
#include <hip/hip_runtime.h>
#include <math.h>

#define PCNT 2048
#define CDIM 512
#define CAP_B (PCNT * 9)        // worst-case entries/batch (box spans <=3x3 cells)

// ------------------------------------------------------------------
// K1: xr = inputs @ W.T + b ; logit = softmax(xr) -> out[row*4+c]
// 16 lanes per row; W staged in LDS swizzled for conflict-free b128.
// Also zero-fills keys[] (graph-captured hipMemsetAsync was ~39us).
// ------------------------------------------------------------------
__global__ __launch_bounds__(256) void k_gemv_softmax(
    const float* __restrict__ in, const float* __restrict__ W,
    const float* __restrict__ bias, float* __restrict__ out,
    unsigned long long* __restrict__ keys, int nkeys)
{
    __shared__ float4 w_lds[512];   // [(m*4+c)*16 + k] = W[c][k*32 + m*4 .. +3]
    int tid = threadIdx.x;
    int gid = blockIdx.x * 256 + tid;
    if (gid < nkeys) keys[gid] = 0ull;
    const float4* W4 = (const float4*)W;   // [c*128 + q]
    for (int e = tid; e < 512; e += 256) {
        int m = e >> 6, rem = e & 63, c = rem >> 4, k = rem & 15;
        w_lds[e] = W4[c * 128 + k * 8 + m];
    }
    __syncthreads();
    int row = blockIdx.x * 16 + (tid >> 4);
    int k   = tid & 15;
    const float4* ip = (const float4*)(in + (size_t)row * CDIM);
    float4 v[8];
#pragma unroll
    for (int m = 0; m < 8; ++m) v[m] = ip[k * 8 + m];
    float a0 = 0.f, a1 = 0.f, a2 = 0.f, a3 = 0.f;
#pragma unroll
    for (int m = 0; m < 8; ++m) {
        float4 w0 = w_lds[(m * 4 + 0) * 16 + k];
        float4 w1 = w_lds[(m * 4 + 1) * 16 + k];
        float4 w2 = w_lds[(m * 4 + 2) * 16 + k];
        float4 w3 = w_lds[(m * 4 + 3) * 16 + k];
        a0 += v[m].x*w0.x + v[m].y*w0.y + v[m].z*w0.z + v[m].w*w0.w;
        a1 += v[m].x*w1.x + v[m].y*w1.y + v[m].z*w1.z + v[m].w*w1.w;
        a2 += v[m].x*w2.x + v[m].y*w2.y + v[m].z*w2.z + v[m].w*w2.w;
        a3 += v[m].x*w3.x + v[m].y*w3.y + v[m].z*w3.z + v[m].w*w3.w;
    }
#pragma unroll
    for (int off = 1; off < 16; off <<= 1) {
        a0 += __shfl_xor(a0, off, 64);
        a1 += __shfl_xor(a1, off, 64);
        a2 += __shfl_xor(a2, off, 64);
        a3 += __shfl_xor(a3, off, 64);
    }
    if (k == 0) {
        a0 += bias[0]; a1 += bias[1]; a2 += bias[2]; a3 += bias[3];
        float m = fmaxf(fmaxf(a0, a1), fmaxf(a2, a3));
        float e0 = expf(a0 - m), e1 = expf(a1 - m), e2 = expf(a2 - m), e3 = expf(a3 - m);
        float inv = 1.f / (e0 + e1 + e2 + e3);
        ((float4*)out)[row] = make_float4(e0 * inv, e1 * inv, e2 * inv, e3 * inv);
    }
}

// ------------------------------------------------------------------
// K2: fused seeds + spatial binning. One 1024-thr block per batch.
// (verified structure from R4) LDS count/prefix/cursor -> no global
// zero-init races. Entry = float4 box + float4(m0,m1,m2,j).
// ------------------------------------------------------------------
__global__ __launch_bounds__(1024) void k_prep(
    const float* __restrict__ rois, const float* __restrict__ ps,
    int* __restrict__ cellStart, int* __restrict__ cellCnt,
    float4* __restrict__ roisE, float4* __restrict__ metaE)
{
    __shared__ float sval[3][1024];
    __shared__ int   sidx[3][1024];
    __shared__ int   scnt[3][1024];
    __shared__ int   amax[3], totc[3];
    __shared__ int   cnt64[64], st64[64], cur64[64];

    int b = blockIdx.x, tid = threadIdx.x;
    const float4* psb = (const float4*)ps + (size_t)b * PCNT;
    const float4* rb  = (const float4*)rois + (size_t)b * PCNT;

    float4 p1 = psb[tid], p2 = psb[tid + 1024];
    {
        float v1, v2; int take;
        v1 = p1.x; v2 = p2.x; take = v2 > v1;
        sval[0][tid] = take ? v2 : v1; sidx[0][tid] = take ? tid + 1024 : tid;
        scnt[0][tid] = (v1 > 0.5f) + (v2 > 0.5f);
        v1 = p1.y; v2 = p2.y; take = v2 > v1;
        sval[1][tid] = take ? v2 : v1; sidx[1][tid] = take ? tid + 1024 : tid;
        scnt[1][tid] = (v1 > 0.5f) + (v2 > 0.5f);
        v1 = p1.z; v2 = p2.z; take = v2 > v1;
        sval[2][tid] = take ? v2 : v1; sidx[2][tid] = take ? tid + 1024 : tid;
        scnt[2][tid] = (v1 > 0.5f) + (v2 > 0.5f);
    }
    __syncthreads();
    for (int s = 512; s > 0; s >>= 1) {
        if (tid < s) {
#pragma unroll
            for (int c = 0; c < 3; ++c) {
                float v2 = sval[c][tid + s]; int i2 = sidx[c][tid + s];
                if (v2 > sval[c][tid] || (v2 == sval[c][tid] && i2 < sidx[c][tid])) {
                    sval[c][tid] = v2; sidx[c][tid] = i2;
                }
                scnt[c][tid] += scnt[c][tid + s];
            }
        }
        __syncthreads();
    }
    if (tid < 3) { amax[tid] = sidx[tid][0]; totc[tid] = scnt[tid][0]; }
    if (tid < 64) cnt64[tid] = 0;
    __syncthreads();

    // count pass (all boxes)
    for (int j = tid; j < PCNT; j += 1024) {
        float4 q = rb[j];
        int cx0 = min(((int)q.x) >> 7, 7), cx1 = min(((int)q.z) >> 7, 7);
        int cy0 = min(((int)q.y) >> 7, 7), cy1 = min(((int)q.w) >> 7, 7);
        for (int cy = cy0; cy <= cy1; ++cy)
            for (int cx = cx0; cx <= cx1; ++cx)
                atomicAdd(&cnt64[cy * 8 + cx], 1);
    }
    __syncthreads();
    if (tid == 0) {
        int a = 0;
        for (int kk = 0; kk < 64; ++kk) { st64[kk] = a; a += cnt64[kk]; }
    }
    __syncthreads();
    if (tid < 64) {
        cur64[tid] = st64[tid];
        cellStart[b * 64 + tid] = st64[tid];
        cellCnt[b * 64 + tid]   = cnt64[tid];
    }
    __syncthreads();

    // scatter pass
    for (int j = tid; j < PCNT; j += 1024) {
        float4 q  = rb[j];
        float4 pv = psb[j];
        float m0 = ((totc[0] <= 1) ? (j == amax[0]) : (pv.x > 0.5f)) ? 1.f : 0.f;
        float m1 = ((totc[1] <= 1) ? (j == amax[1]) : (pv.y > 0.5f)) ? 1.f : 0.f;
        float m2 = ((totc[2] <= 1) ? (j == amax[2]) : (pv.z > 0.5f)) ? 1.f : 0.f;
        float4 meta = make_float4(m0, m1, m2, __int_as_float(j));
        int cx0 = min(((int)q.x) >> 7, 7), cx1 = min(((int)q.z) >> 7, 7);
        int cy0 = min(((int)q.y) >> 7, 7), cy1 = min(((int)q.w) >> 7, 7);
        for (int cy = cy0; cy <= cy1; ++cy)
            for (int cx = cx0; cx <= cx1; ++cx) {
                int e = atomicAdd(&cur64[cy * 8 + cx], 1);
                size_t idx = (size_t)b * CAP_B + e;
                roisE[idx] = q;
                metaE[idx] = meta;
            }
    }
}

// ------------------------------------------------------------------
// K3: assignment, self-scheduled. Grid = B*64 blocks of 256 (4 waves).
// Each wave: load 64 cellCnt, shfl prefix-scan -> (group-count prefix,
// entry prefix), then loop items idx = widx, widx+256, ... Per item:
// ballot+ffs locates (cell, g); 8 i-entries x 8 j-lanes scan the cell
// list; u64 key = (iou_bits<<32)|(0x7FFFFFFF-j); guarded atomicMax.
// ------------------------------------------------------------------
__global__ __launch_bounds__(256) void k_assign3(
    const int* __restrict__ cellCnt, const int* __restrict__ cellStart,
    const float4* __restrict__ roisE, const float4* __restrict__ metaE,
    unsigned long long* __restrict__ keys)
{
    int tid = threadIdx.x;
    int b = blockIdx.x >> 6;
    int lane = tid & 63;
    int cnt   = cellCnt[b * 64 + lane];
    int start = cellStart[b * 64 + lane];
    int grp = (cnt + 7) >> 3;
    int ginc = grp;
#pragma unroll
    for (int d = 1; d < 64; d <<= 1) {
        int v = __shfl_up(ginc, d, 64);
        if (lane >= d) ginc += v;
    }
    int gexc = ginc - grp;
    int total = __shfl(ginc, 63, 64);
    int widx = ((blockIdx.x & 63) << 2) + (tid >> 6);
    int il = lane >> 3, jl = lane & 7;

    for (int idx = widx; idx < total; idx += 256) {
        unsigned long long msk = __ballot(idx >= gexc && idx < ginc);
        int cell = __ffsll((unsigned long long)msk) - 1;
        int g = idx - __shfl(gexc, cell, 64);
        int n = __shfl(cnt, cell, 64);
        size_t base = (size_t)b * CAP_B + __shfl(start, cell, 64);
        int ie = g * 8 + il;
        bool ivalid = ie < n;
        int iload = ivalid ? ie : 0;
        float4 r = roisE[base + iload];
        int i_prop = __float_as_int(metaE[base + iload].w);
        float areaA = (r.z - r.x) * (r.w - r.y);

        unsigned long long best0 = 0, best1 = 0, best2 = 0;
        for (int e = jl; e < n; e += 8) {
            float4 q = roisE[base + e];
            float4 m = metaE[base + e];
            float lx = fmaxf(r.x, q.x), ly = fmaxf(r.y, q.y);
            float rx = fminf(r.z, q.z), ry = fminf(r.w, q.w);
            float ww = fmaxf(rx - lx, 0.f);
            float hh = fmaxf(ry - ly, 0.f);
            float inter = ww * hh;
            float areaB = (q.z - q.x) * (q.w - q.y);
            float u = (areaA + areaB) - inter;
            float ioup1 = fmaf(inter, __builtin_amdgcn_rcpf(u), 1.0f);   // iou+1
            unsigned lo = 0x7FFFFFFFu - (unsigned)__float_as_int(m.w);
            float t0 = fmaxf(fmaf(ioup1, m.x, -1.0f), 0.f);   // seed? iou : 0
            float t1 = fmaxf(fmaf(ioup1, m.y, -1.0f), 0.f);
            float t2 = fmaxf(fmaf(ioup1, m.z, -1.0f), 0.f);
            unsigned long long k0 = ((unsigned long long)(unsigned)__float_as_int(t0) << 32) | lo;
            unsigned long long k1 = ((unsigned long long)(unsigned)__float_as_int(t1) << 32) | lo;
            unsigned long long k2 = ((unsigned long long)(unsigned)__float_as_int(t2) << 32) | lo;
            if (k0 > best0) best0 = k0;
            if (k1 > best1) best1 = k1;
            if (k2 > best2) best2 = k2;
        }
#pragma unroll
        for (int off = 1; off < 8; off <<= 1) {
            unsigned long long o;
            o = __shfl_xor(best0, off, 64); if (o > best0) best0 = o;
            o = __shfl_xor(best1, off, 64); if (o > best1) best1 = o;
            o = __shfl_xor(best2, off, 64); if (o > best2) best2 = o;
        }
        if (jl == 0 && ivalid) {
            size_t kb = ((size_t)b * PCNT + i_prop) * 3;
            if ((unsigned)(best0 >> 32) >= 0x3F000000u) atomicMax(&keys[kb + 0], best0);
            if ((unsigned)(best1 >> 32) >= 0x3F000000u) atomicMax(&keys[kb + 1], best1);
            if ((unsigned)(best2 >> 32) >= 0x3F000000u) atomicMax(&keys[kb + 2], best2);
        }
    }
}

// ------------------------------------------------------------------
// Fallback path (ws too small): seeds-only kernel + full-scan assign.
// ------------------------------------------------------------------
__global__ __launch_bounds__(256) void k_seeds_only(
    const float* __restrict__ ps, int* __restrict__ seedsCnt,
    int* __restrict__ seedsAmax)
{
    int b = blockIdx.x / 3, c = blockIdx.x % 3;
    int tid = threadIdx.x;
    __shared__ float sval[256];
    __shared__ int   sidx[256];
    __shared__ int   scnt[256];
    float bestv = -1e30f; int besti = 0; int cnt = 0;
#pragma unroll
    for (int t = 0; t < PCNT / 256; ++t) {
        int j = tid + t * 256;
        float v = ps[((size_t)b * PCNT + j) * 4 + c];
        if (v > 0.5f) cnt++;
        if (v > bestv) { bestv = v; besti = j; }
    }
    sval[tid] = bestv; sidx[tid] = besti; scnt[tid] = cnt;
    __syncthreads();
    for (int s = 128; s > 0; s >>= 1) {
        if (tid < s) {
            float v2 = sval[tid + s]; int i2 = sidx[tid + s];
            if (v2 > sval[tid] || (v2 == sval[tid] && i2 < sidx[tid])) { sval[tid] = v2; sidx[tid] = i2; }
            scnt[tid] += scnt[tid + s];
        }
        __syncthreads();
    }
    if (tid == 0) { seedsCnt[b * 3 + c] = scnt[0]; seedsAmax[b * 3 + c] = sidx[0]; }
}

__global__ __launch_bounds__(256) void k_assign_fallback(
    const float* __restrict__ rois, const float* __restrict__ ps,
    const int* __restrict__ seedsCnt, const int* __restrict__ seedsAmax,
    unsigned long long* __restrict__ keys)
{
    int tid = threadIdx.x;
    int item = blockIdx.x * 4 + (tid >> 6);
    int b = item >> 8;
    int g = item & 255;
    int lane = tid & 63, il = lane >> 3, jl = lane & 7;
    int ie = g * 8 + il;
    const float4* rb = (const float4*)rois + (size_t)b * PCNT;
    const float4* pb = (const float4*)ps + (size_t)b * PCNT;
    float4 r = rb[ie];
    float areaA = (r.z - r.x) * (r.w - r.y);
    int c0 = seedsCnt[b*3+0], a0 = seedsAmax[b*3+0];
    int c1 = seedsCnt[b*3+1], a1 = seedsAmax[b*3+1];
    int c2 = seedsCnt[b*3+2], a2 = seedsAmax[b*3+2];

    unsigned long long best0 = 0, best1 = 0, best2 = 0;
    for (int e = jl; e < PCNT; e += 8) {
        float4 q = rb[e];
        float4 pv = pb[e];
        float m0 = ((c0 <= 1) ? (e == a0) : (pv.x > 0.5f)) ? 1.f : 0.f;
        float m1 = ((c1 <= 1) ? (e == a1) : (pv.y > 0.5f)) ? 1.f : 0.f;
        float m2 = ((c2 <= 1) ? (e == a2) : (pv.z > 0.5f)) ? 1.f : 0.f;
        float lx = fmaxf(r.x, q.x), ly = fmaxf(r.y, q.y);
        float rx = fminf(r.z, q.z), ry = fminf(r.w, q.w);
        float ww = fmaxf(rx - lx, 0.f);
        float hh = fmaxf(ry - ly, 0.f);
        float inter = ww * hh;
        float areaB = (q.z - q.x) * (q.w - q.y);
        float u = (areaA + areaB) - inter;
        float ioup1 = fmaf(inter, __builtin_amdgcn_rcpf(u), 1.0f);
        unsigned lo = 0x7FFFFFFFu - (unsigned)e;
        float t0 = fmaxf(fmaf(ioup1, m0, -1.0f), 0.f);
        float t1 = fmaxf(fmaf(ioup1, m1, -1.0f), 0.f);
        float t2 = fmaxf(fmaf(ioup1, m2, -1.0f), 0.f);
        unsigned long long k0 = ((unsigned long long)(unsigned)__float_as_int(t0) << 32) | lo;
        unsigned long long k1 = ((unsigned long long)(unsigned)__float_as_int(t1) << 32) | lo;
        unsigned long long k2 = ((unsigned long long)(unsigned)__float_as_int(t2) << 32) | lo;
        if (k0 > best0) best0 = k0;
        if (k1 > best1) best1 = k1;
        if (k2 > best2) best2 = k2;
    }
#pragma unroll
    for (int off = 1; off < 8; off <<= 1) {
        unsigned long long o;
        o = __shfl_xor(best0, off, 64); if (o > best0) best0 = o;
        o = __shfl_xor(best1, off, 64); if (o > best1) best1 = o;
        o = __shfl_xor(best2, off, 64); if (o > best2) best2 = o;
    }
    if (jl == 0) {
        size_t kb = ((size_t)b * PCNT + ie) * 3;
        if ((unsigned)(best0 >> 32) >= 0x3F000000u) atomicMax(&keys[kb + 0], best0);
        if ((unsigned)(best1 >> 32) >= 0x3F000000u) atomicMax(&keys[kb + 1], best1);
        if ((unsigned)(best2 >> 32) >= 0x3F000000u) atomicMax(&keys[kb + 2], best2);
    }
}

// ------------------------------------------------------------------
// K4: finalize assignment + per-class partial loss sums/counts.
// Shfl-based reduction (1 syncthreads instead of 64).
// ------------------------------------------------------------------
__global__ __launch_bounds__(256) void k_finalize_loss(
    const unsigned long long* __restrict__ keys, const float* __restrict__ ps,
    const float* __restrict__ labels, const float* __restrict__ logit,
    float* __restrict__ partials, int rows)
{
    int tid = threadIdx.x;
    int row = blockIdx.x * 256 + tid;
    float vals[8] = {0.f, 0.f, 0.f, 0.f, 0.f, 0.f, 0.f, 0.f};
    if (row < rows) {
        int b = row >> 11;
        float I = -1.f; int cls = 3; float wv = 1.f;
#pragma unroll
        for (int c = 0; c < 3; ++c) {
            unsigned long long key = keys[(size_t)row * 3 + c];
            float lab = labels[b * 4 + c];
            if (key != 0ull && lab > 0.f) {
                float t = __uint_as_float((unsigned)(key >> 32));
                if (t >= 0.5f && t > I) {
                    int j = 0x7FFFFFFF - (int)(key & 0xFFFFFFFFull);
                    I = t; cls = c;
                    wv = ps[((size_t)b * PCNT + j) * 4 + c];
                }
            }
        }
        float4 lg = ((const float4*)logit)[row];
        float l = (cls == 0) ? lg.x : (cls == 1) ? lg.y : (cls == 2) ? lg.z : lg.w;
        float p = fminf(fmaxf(l, 1e-7f), 1.f - 1e-7f);
        float om = 1.f - p;
        float fl = -logf(p) * om * om;
        float lab = (cls == 3) ? 1.f : labels[b * 4 + cls];
        float wu = 10.f * expf(l) * (1.f - lab) + lab;
        float contrib = wv * fl * wu;
        vals[0] = (cls == 0) ? contrib : 0.f; vals[4] = (cls == 0) ? 1.f : 0.f;
        vals[1] = (cls == 1) ? contrib : 0.f; vals[5] = (cls == 1) ? 1.f : 0.f;
        vals[2] = (cls == 2) ? contrib : 0.f; vals[6] = (cls == 2) ? 1.f : 0.f;
        vals[3] = (cls == 3) ? contrib : 0.f; vals[7] = (cls == 3) ? 1.f : 0.f;
    }
#pragma unroll
    for (int comp = 0; comp < 8; ++comp) {
#pragma unroll
        for (int off = 1; off < 64; off <<= 1)
            vals[comp] += __shfl_xor(vals[comp], off, 64);
    }
    __shared__ float wred[4][8];
    int lane = tid & 63, wave = tid >> 6;
    if (lane == 0) {
#pragma unroll
        for (int comp = 0; comp < 8; ++comp) wred[wave][comp] = vals[comp];
    }
    __syncthreads();
    if (tid < 8)
        partials[blockIdx.x * 8 + tid] =
            wred[0][tid] + wred[1][tid] + wred[2][tid] + wred[3][tid];
}

// ------------------------------------------------------------------
// K5: final reduce: loss = sum_c S_c / (N_c + 1e-7) / B   (nblk=128)
// ------------------------------------------------------------------
__global__ __launch_bounds__(128) void k_loss_final3(
    const float* __restrict__ partials, float* __restrict__ out_loss, float invB)
{
    __shared__ float red[128];
    int tid = threadIdx.x;
    int c = tid & 7, i = tid >> 3;   // i in [0,16)
    float s = 0.f;
    for (int kb = i; kb < 128; kb += 16) s += partials[kb * 8 + c];
    red[c * 16 + i] = s;
    __syncthreads();
    for (int st = 8; st > 0; st >>= 1) {
        if (i < st) red[c * 16 + i] += red[c * 16 + i + st];
        __syncthreads();
    }
    if (tid == 0) {
        float loss = 0.f;
#pragma unroll
        for (int cc = 0; cc < 4; ++cc)
            loss += red[cc * 16] / (red[(cc + 4) * 16] + 1e-7f);
        *out_loss = loss * invB;
    }
}

extern "C" void kernel_launch(void* const* d_in, const int* in_sizes, int n_in,
                              void* d_out, int out_size, void* d_ws, size_t ws_size,
                              hipStream_t stream)
{
    const float* inputs = (const float*)d_in[0];
    const float* ps     = (const float*)d_in[1];
    const float* labels = (const float*)d_in[2];
    const float* rois   = (const float*)d_in[3];
    const float* fcw    = (const float*)d_in[4];
    const float* fcb    = (const float*)d_in[5];

    int B = in_sizes[2] / 4;            // 16
    int rows = B * PCNT;                // 32768
    float* out = (float*)d_out;

    char* ws = (char*)d_ws;
    size_t off = 0;
    unsigned long long* keys = (unsigned long long*)(ws + off);
    int nkeys = rows * 3;
    off += (size_t)nkeys * 8;
    off = (off + 255) & ~(size_t)255;
    float* partials = (float*)(ws + off);               off += 128 * 8 * 4;
    int* seedsCnt  = (int*)(ws + off);                  off += (size_t)B * 3 * 4;
    int* seedsAmax = (int*)(ws + off);                  off += (size_t)B * 3 * 4;
    off = (off + 255) & ~(size_t)255;
    int* cellCnt   = (int*)(ws + off);                  off += (size_t)B * 64 * 4;
    int* cellStart = (int*)(ws + off);                  off += (size_t)B * 64 * 4;
    off = (off + 255) & ~(size_t)255;
    float4* roisE = (float4*)(ws + off);                off += (size_t)B * CAP_B * 16;
    float4* metaE = (float4*)(ws + off);                off += (size_t)B * CAP_B * 16;
    bool binned = (ws_size >= off);

    k_gemv_softmax<<<rows / 16, 256, 0, stream>>>(inputs, fcw, fcb, out, keys, nkeys);
    if (binned) {
        k_prep<<<B, 1024, 0, stream>>>(rois, ps, cellStart, cellCnt, roisE, metaE);
        k_assign3<<<B * 64, 256, 0, stream>>>(cellCnt, cellStart, roisE, metaE, keys);
    } else {
        k_seeds_only<<<B * 3, 256, 0, stream>>>(ps, seedsCnt, seedsAmax);
        k_assign_fallback<<<B * 64, 256, 0, stream>>>(rois, ps, seedsCnt, seedsAmax, keys);
    }
    const int NBLK = 128;   // rows/256
    k_finalize_loss<<<NBLK, 256, 0, stream>>>(keys, ps, labels, out, partials, rows);
    k_loss_final3<<<1, 128, 0, stream>>>(partials, out + (size_t)rows * 4, 1.f / (float)B);
}

// Round 8
// 76.229 us; speedup vs baseline: 1.6956x; 1.0086x over previous
//
#include <hip/hip_runtime.h>
#include <math.h>

#define PCNT 2048
#define CDIM 512
#define CAP_B (PCNT * 9)        // worst-case entries/batch (box spans <=3x3 cells)

// ------------------------------------------------------------------
// K1 mega: role by blockIdx.
//  [0, gemvBlocks): gemv+softmax (16 lanes/row, coalesced 256B/instr
//    loads), zero keys[] and doneCnt.
//  [gemvBlocks, +3B): seeds per (b,c): cnt(>0.5), first argmax.
//  [+3B, +3B+8B): cell counts per (b, cy): direct write, no atomics
//    on global, no zero-init needed.
// ------------------------------------------------------------------
__global__ __launch_bounds__(256) void k_mega(
    const float* __restrict__ in, const float* __restrict__ W,
    const float* __restrict__ bias, float* __restrict__ out,
    unsigned long long* __restrict__ keys, int nkeys,
    unsigned* __restrict__ doneCnt,
    const float* __restrict__ ps, int* __restrict__ seedsCnt,
    int* __restrict__ seedsAmax,
    const float* __restrict__ rois, int* __restrict__ cellCnt,
    int gemvBlocks, int B)
{
    __shared__ float4 w_lds[512];     // [q*4+c] = W[c][q*4..q*4+3]
    __shared__ float sval[256];
    __shared__ int   sidx[256];
    __shared__ int   scnt[256];
    __shared__ int   cnt8[8];
    int tid = threadIdx.x;
    int bid = blockIdx.x;

    if (bid < gemvBlocks) {
        // ---------------- GEMV + softmax ----------------
        int gid = bid * 256 + tid;
        if (gid < nkeys) keys[gid] = 0ull;
        if (gid == 0) *doneCnt = 0u;
        const float4* W4 = (const float4*)W;   // [c*128 + q]
        for (int e = tid; e < 512; e += 256) {
            int q = e >> 2, c = e & 3;
            w_lds[e] = W4[c * 128 + q];
        }
        __syncthreads();
        int row = bid * 16 + (tid >> 4);
        int k   = tid & 15;
        const float4* ip = (const float4*)(in + (size_t)row * CDIM);
        float4 v[8];
#pragma unroll
        for (int m = 0; m < 8; ++m) v[m] = ip[m * 16 + k];   // 256B/instr contiguous
        float a0 = 0.f, a1 = 0.f, a2 = 0.f, a3 = 0.f;
#pragma unroll
        for (int m = 0; m < 8; ++m) {
            int q = m * 16 + k;
            float4 w0 = w_lds[q * 4 + 0];
            float4 w1 = w_lds[q * 4 + 1];
            float4 w2 = w_lds[q * 4 + 2];
            float4 w3 = w_lds[q * 4 + 3];
            a0 += v[m].x*w0.x + v[m].y*w0.y + v[m].z*w0.z + v[m].w*w0.w;
            a1 += v[m].x*w1.x + v[m].y*w1.y + v[m].z*w1.z + v[m].w*w1.w;
            a2 += v[m].x*w2.x + v[m].y*w2.y + v[m].z*w2.z + v[m].w*w2.w;
            a3 += v[m].x*w3.x + v[m].y*w3.y + v[m].z*w3.z + v[m].w*w3.w;
        }
#pragma unroll
        for (int off = 1; off < 16; off <<= 1) {
            a0 += __shfl_xor(a0, off, 64);
            a1 += __shfl_xor(a1, off, 64);
            a2 += __shfl_xor(a2, off, 64);
            a3 += __shfl_xor(a3, off, 64);
        }
        if (k == 0) {
            a0 += bias[0]; a1 += bias[1]; a2 += bias[2]; a3 += bias[3];
            float m = fmaxf(fmaxf(a0, a1), fmaxf(a2, a3));
            float e0 = expf(a0 - m), e1 = expf(a1 - m), e2 = expf(a2 - m), e3 = expf(a3 - m);
            float inv = 1.f / (e0 + e1 + e2 + e3);
            ((float4*)out)[row] = make_float4(e0 * inv, e1 * inv, e2 * inv, e3 * inv);
        }
    } else if (bid < gemvBlocks + 3 * B) {
        // ---------------- seeds per (b,c) ----------------
        int idx = bid - gemvBlocks;
        int b = idx / 3, c = idx % 3;
        const float4* psb = (const float4*)ps + (size_t)b * PCNT;
        float bestv = -1e30f; int besti = 0; int cnt = 0;
#pragma unroll
        for (int t = 0; t < PCNT / 256; ++t) {
            int j = tid + t * 256;
            float4 pv = psb[j];
            float vv = (c == 0) ? pv.x : ((c == 1) ? pv.y : pv.z);
            if (vv > 0.5f) cnt++;
            if (vv > bestv) { bestv = vv; besti = j; }   // ascending j -> first max
        }
        sval[tid] = bestv; sidx[tid] = besti; scnt[tid] = cnt;
        __syncthreads();
        for (int s = 128; s > 0; s >>= 1) {
            if (tid < s) {
                float v2 = sval[tid + s]; int i2 = sidx[tid + s];
                if (v2 > sval[tid] || (v2 == sval[tid] && i2 < sidx[tid])) { sval[tid] = v2; sidx[tid] = i2; }
                scnt[tid] += scnt[tid + s];
            }
            __syncthreads();
        }
        if (tid == 0) { seedsCnt[idx] = scnt[0]; seedsAmax[idx] = sidx[0]; }
    } else {
        // ---------------- cell count per (b, cy) ----------------
        int idx = bid - gemvBlocks - 3 * B;
        int b = idx >> 3, cy = idx & 7;
        if (tid < 8) cnt8[tid] = 0;
        __syncthreads();
        const float4* rb = (const float4*)rois + (size_t)b * PCNT;
#pragma unroll
        for (int t = 0; t < PCNT / 256; ++t) {
            int j = tid + t * 256;
            float4 q = rb[j];
            int cy0 = min(((int)q.y) >> 7, 7), cy1 = min(((int)q.w) >> 7, 7);
            if (cy0 <= cy && cy <= cy1) {
                int cx0 = min(((int)q.x) >> 7, 7), cx1 = min(((int)q.z) >> 7, 7);
                for (int cx = cx0; cx <= cx1; ++cx) atomicAdd(&cnt8[cx], 1);
            }
        }
        __syncthreads();
        if (tid < 8) cellCnt[b * 64 + cy * 8 + tid] = cnt8[tid];
    }
}

// ------------------------------------------------------------------
// K2: scan + scatter. One 256-thr block per batch. Wave 0 prefix-scans
// the 64 cell counts; all threads scatter entries via LDS cursors.
// ------------------------------------------------------------------
__global__ __launch_bounds__(256) void k_scan_scatter(
    const float* __restrict__ rois, const float* __restrict__ ps,
    const int* __restrict__ seedsCnt, const int* __restrict__ seedsAmax,
    const int* __restrict__ cellCnt, int* __restrict__ cellStart,
    float4* __restrict__ roisE, float4* __restrict__ metaE)
{
    __shared__ int cur64[64];
    int b = blockIdx.x, tid = threadIdx.x;
    if (tid < 64) {
        int cnt = cellCnt[b * 64 + tid];
        int incl = cnt;
#pragma unroll
        for (int d = 1; d < 64; d <<= 1) {
            int v = __shfl_up(incl, d, 64);
            if (tid >= d) incl += v;
        }
        int excl = incl - cnt;
        cellStart[b * 64 + tid] = excl;
        cur64[tid] = excl;
    }
    __syncthreads();
    int sc0 = seedsCnt[b*3+0], sa0 = seedsAmax[b*3+0];
    int sc1 = seedsCnt[b*3+1], sa1 = seedsAmax[b*3+1];
    int sc2 = seedsCnt[b*3+2], sa2 = seedsAmax[b*3+2];
    const float4* rb  = (const float4*)rois + (size_t)b * PCNT;
    const float4* psb = (const float4*)ps + (size_t)b * PCNT;
#pragma unroll
    for (int t = 0; t < PCNT / 256; ++t) {
        int j = tid + t * 256;
        float4 q  = rb[j];
        float4 pv = psb[j];
        float m0 = ((sc0 <= 1) ? (j == sa0) : (pv.x > 0.5f)) ? 1.f : 0.f;
        float m1 = ((sc1 <= 1) ? (j == sa1) : (pv.y > 0.5f)) ? 1.f : 0.f;
        float m2 = ((sc2 <= 1) ? (j == sa2) : (pv.z > 0.5f)) ? 1.f : 0.f;
        float4 meta = make_float4(m0, m1, m2, __int_as_float(j));
        int cx0 = min(((int)q.x) >> 7, 7), cx1 = min(((int)q.z) >> 7, 7);
        int cy0 = min(((int)q.y) >> 7, 7), cy1 = min(((int)q.w) >> 7, 7);
        for (int cy = cy0; cy <= cy1; ++cy)
            for (int cx = cx0; cx <= cx1; ++cx) {
                int e = atomicAdd(&cur64[cy * 8 + cx], 1);
                size_t pos = (size_t)b * CAP_B + e;
                roisE[pos] = q;
                metaE[pos] = meta;
            }
    }
}

// ------------------------------------------------------------------
// K3: assignment, self-scheduled (proven R7). Grid = B*64 x 256.
// ------------------------------------------------------------------
__global__ __launch_bounds__(256) void k_assign3(
    const int* __restrict__ cellCnt, const int* __restrict__ cellStart,
    const float4* __restrict__ roisE, const float4* __restrict__ metaE,
    unsigned long long* __restrict__ keys)
{
    int tid = threadIdx.x;
    int b = blockIdx.x >> 6;
    int lane = tid & 63;
    int cnt   = cellCnt[b * 64 + lane];
    int start = cellStart[b * 64 + lane];
    int grp = (cnt + 7) >> 3;
    int ginc = grp;
#pragma unroll
    for (int d = 1; d < 64; d <<= 1) {
        int v = __shfl_up(ginc, d, 64);
        if (lane >= d) ginc += v;
    }
    int gexc = ginc - grp;
    int total = __shfl(ginc, 63, 64);
    int widx = ((blockIdx.x & 63) << 2) + (tid >> 6);
    int il = lane >> 3, jl = lane & 7;

    for (int idx = widx; idx < total; idx += 256) {
        unsigned long long msk = __ballot(idx >= gexc && idx < ginc);
        int cell = __ffsll((unsigned long long)msk) - 1;
        int g = idx - __shfl(gexc, cell, 64);
        int n = __shfl(cnt, cell, 64);
        size_t base = (size_t)b * CAP_B + __shfl(start, cell, 64);
        int ie = g * 8 + il;
        bool ivalid = ie < n;
        int iload = ivalid ? ie : 0;
        float4 r = roisE[base + iload];
        int i_prop = __float_as_int(metaE[base + iload].w);
        float areaA = (r.z - r.x) * (r.w - r.y);

        unsigned long long best0 = 0, best1 = 0, best2 = 0;
        for (int e = jl; e < n; e += 8) {
            float4 q = roisE[base + e];
            float4 m = metaE[base + e];
            float lx = fmaxf(r.x, q.x), ly = fmaxf(r.y, q.y);
            float rx = fminf(r.z, q.z), ry = fminf(r.w, q.w);
            float ww = fmaxf(rx - lx, 0.f);
            float hh = fmaxf(ry - ly, 0.f);
            float inter = ww * hh;
            float areaB = (q.z - q.x) * (q.w - q.y);
            float u = (areaA + areaB) - inter;
            float ioup1 = fmaf(inter, __builtin_amdgcn_rcpf(u), 1.0f);   // iou+1
            unsigned lo = 0x7FFFFFFFu - (unsigned)__float_as_int(m.w);
            float t0 = fmaxf(fmaf(ioup1, m.x, -1.0f), 0.f);   // seed? iou : 0
            float t1 = fmaxf(fmaf(ioup1, m.y, -1.0f), 0.f);
            float t2 = fmaxf(fmaf(ioup1, m.z, -1.0f), 0.f);
            unsigned long long k0 = ((unsigned long long)(unsigned)__float_as_int(t0) << 32) | lo;
            unsigned long long k1 = ((unsigned long long)(unsigned)__float_as_int(t1) << 32) | lo;
            unsigned long long k2 = ((unsigned long long)(unsigned)__float_as_int(t2) << 32) | lo;
            if (k0 > best0) best0 = k0;
            if (k1 > best1) best1 = k1;
            if (k2 > best2) best2 = k2;
        }
#pragma unroll
        for (int off = 1; off < 8; off <<= 1) {
            unsigned long long o;
            o = __shfl_xor(best0, off, 64); if (o > best0) best0 = o;
            o = __shfl_xor(best1, off, 64); if (o > best1) best1 = o;
            o = __shfl_xor(best2, off, 64); if (o > best2) best2 = o;
        }
        if (jl == 0 && ivalid) {
            size_t kb = ((size_t)b * PCNT + i_prop) * 3;
            if ((unsigned)(best0 >> 32) >= 0x3F000000u) atomicMax(&keys[kb + 0], best0);
            if ((unsigned)(best1 >> 32) >= 0x3F000000u) atomicMax(&keys[kb + 1], best1);
            if ((unsigned)(best2 >> 32) >= 0x3F000000u) atomicMax(&keys[kb + 2], best2);
        }
    }
}

// ------------------------------------------------------------------
// Fallback (ws too small): full scan, wave per 8 i's, same keys.
// ------------------------------------------------------------------
__global__ __launch_bounds__(256) void k_assign_fallback(
    const float* __restrict__ rois, const float* __restrict__ ps,
    const int* __restrict__ seedsCnt, const int* __restrict__ seedsAmax,
    unsigned long long* __restrict__ keys)
{
    int tid = threadIdx.x;
    int item = blockIdx.x * 4 + (tid >> 6);
    int b = item >> 8;
    int g = item & 255;
    int lane = tid & 63, il = lane >> 3, jl = lane & 7;
    int ie = g * 8 + il;
    const float4* rb = (const float4*)rois + (size_t)b * PCNT;
    const float4* pb = (const float4*)ps + (size_t)b * PCNT;
    float4 r = rb[ie];
    float areaA = (r.z - r.x) * (r.w - r.y);
    int c0 = seedsCnt[b*3+0], a0 = seedsAmax[b*3+0];
    int c1 = seedsCnt[b*3+1], a1 = seedsAmax[b*3+1];
    int c2 = seedsCnt[b*3+2], a2 = seedsAmax[b*3+2];

    unsigned long long best0 = 0, best1 = 0, best2 = 0;
    for (int e = jl; e < PCNT; e += 8) {
        float4 q = rb[e];
        float4 pv = pb[e];
        float m0 = ((c0 <= 1) ? (e == a0) : (pv.x > 0.5f)) ? 1.f : 0.f;
        float m1 = ((c1 <= 1) ? (e == a1) : (pv.y > 0.5f)) ? 1.f : 0.f;
        float m2 = ((c2 <= 1) ? (e == a2) : (pv.z > 0.5f)) ? 1.f : 0.f;
        float lx = fmaxf(r.x, q.x), ly = fmaxf(r.y, q.y);
        float rx = fminf(r.z, q.z), ry = fminf(r.w, q.w);
        float ww = fmaxf(rx - lx, 0.f);
        float hh = fmaxf(ry - ly, 0.f);
        float inter = ww * hh;
        float areaB = (q.z - q.x) * (q.w - q.y);
        float u = (areaA + areaB) - inter;
        float ioup1 = fmaf(inter, __builtin_amdgcn_rcpf(u), 1.0f);
        unsigned lo = 0x7FFFFFFFu - (unsigned)e;
        float t0 = fmaxf(fmaf(ioup1, m0, -1.0f), 0.f);
        float t1 = fmaxf(fmaf(ioup1, m1, -1.0f), 0.f);
        float t2 = fmaxf(fmaf(ioup1, m2, -1.0f), 0.f);
        unsigned long long k0 = ((unsigned long long)(unsigned)__float_as_int(t0) << 32) | lo;
        unsigned long long k1 = ((unsigned long long)(unsigned)__float_as_int(t1) << 32) | lo;
        unsigned long long k2 = ((unsigned long long)(unsigned)__float_as_int(t2) << 32) | lo;
        if (k0 > best0) best0 = k0;
        if (k1 > best1) best1 = k1;
        if (k2 > best2) best2 = k2;
    }
#pragma unroll
    for (int off = 1; off < 8; off <<= 1) {
        unsigned long long o;
        o = __shfl_xor(best0, off, 64); if (o > best0) best0 = o;
        o = __shfl_xor(best1, off, 64); if (o > best1) best1 = o;
        o = __shfl_xor(best2, off, 64); if (o > best2) best2 = o;
    }
    if (jl == 0) {
        size_t kb = ((size_t)b * PCNT + ie) * 3;
        if ((unsigned)(best0 >> 32) >= 0x3F000000u) atomicMax(&keys[kb + 0], best0);
        if ((unsigned)(best1 >> 32) >= 0x3F000000u) atomicMax(&keys[kb + 1], best1);
        if ((unsigned)(best2 >> 32) >= 0x3F000000u) atomicMax(&keys[kb + 2], best2);
    }
}

// ------------------------------------------------------------------
// K4: finalize + per-class partials + last-block final reduce.
// loss = sum_c S_c/(N_c+1e-7) / B. Deterministic (fixed sum order).
// ------------------------------------------------------------------
__global__ __launch_bounds__(256) void k_finalize_loss(
    const unsigned long long* __restrict__ keys, const float* __restrict__ ps,
    const float* __restrict__ labels, const float* __restrict__ logit,
    float* __restrict__ partials, unsigned* __restrict__ doneCnt,
    float* __restrict__ out_loss, int rows, float invB)
{
    int tid = threadIdx.x;
    int row = blockIdx.x * 256 + tid;
    float vals[8] = {0.f, 0.f, 0.f, 0.f, 0.f, 0.f, 0.f, 0.f};
    if (row < rows) {
        int b = row >> 11;
        float I = -1.f; int cls = 3; float wv = 1.f;
#pragma unroll
        for (int c = 0; c < 3; ++c) {
            unsigned long long key = keys[(size_t)row * 3 + c];
            float lab = labels[b * 4 + c];
            if (key != 0ull && lab > 0.f) {
                float t = __uint_as_float((unsigned)(key >> 32));
                if (t >= 0.5f && t > I) {
                    int j = 0x7FFFFFFF - (int)(key & 0xFFFFFFFFull);
                    I = t; cls = c;
                    wv = ps[((size_t)b * PCNT + j) * 4 + c];
                }
            }
        }
        float4 lg = ((const float4*)logit)[row];
        float l = (cls == 0) ? lg.x : (cls == 1) ? lg.y : (cls == 2) ? lg.z : lg.w;
        float p = fminf(fmaxf(l, 1e-7f), 1.f - 1e-7f);
        float om = 1.f - p;
        float fl = -logf(p) * om * om;
        float lab = (cls == 3) ? 1.f : labels[b * 4 + cls];
        float wu = 10.f * expf(l) * (1.f - lab) + lab;
        float contrib = wv * fl * wu;
        vals[0] = (cls == 0) ? contrib : 0.f; vals[4] = (cls == 0) ? 1.f : 0.f;
        vals[1] = (cls == 1) ? contrib : 0.f; vals[5] = (cls == 1) ? 1.f : 0.f;
        vals[2] = (cls == 2) ? contrib : 0.f; vals[6] = (cls == 2) ? 1.f : 0.f;
        vals[3] = (cls == 3) ? contrib : 0.f; vals[7] = (cls == 3) ? 1.f : 0.f;
    }
#pragma unroll
    for (int comp = 0; comp < 8; ++comp) {
#pragma unroll
        for (int off = 1; off < 64; off <<= 1)
            vals[comp] += __shfl_xor(vals[comp], off, 64);
    }
    __shared__ float wred[4][8];
    __shared__ bool lastBlk;
    int lane = tid & 63, wave = tid >> 6;
    if (lane == 0) {
#pragma unroll
        for (int comp = 0; comp < 8; ++comp) wred[wave][comp] = vals[comp];
    }
    __syncthreads();
    if (tid < 8) {
        partials[blockIdx.x * 8 + tid] =
            wred[0][tid] + wred[1][tid] + wred[2][tid] + wred[3][tid];
        __threadfence();
    }
    __syncthreads();
    if (tid == 0) {
        unsigned old = atomicAdd(doneCnt, 1u);
        lastBlk = (old == gridDim.x - 1);
    }
    __syncthreads();
    if (lastBlk) {
        __threadfence();
        __shared__ float red[8][32];
        int c = tid & 7, i = tid >> 3;   // i in [0,32)
        float s = 0.f;
        for (int kb = i; kb < (int)gridDim.x; kb += 32) s += partials[kb * 8 + c];
        red[c][i] = s;
        __syncthreads();
        for (int st = 16; st > 0; st >>= 1) {
            if (i < st && tid < 256) red[c][i] += red[c][i + st];
            __syncthreads();
        }
        if (tid == 0) {
            float loss = 0.f;
#pragma unroll
            for (int cc = 0; cc < 4; ++cc)
                loss += red[cc][0] / (red[cc + 4][0] + 1e-7f);
            *out_loss = loss * invB;
        }
    }
}

extern "C" void kernel_launch(void* const* d_in, const int* in_sizes, int n_in,
                              void* d_out, int out_size, void* d_ws, size_t ws_size,
                              hipStream_t stream)
{
    const float* inputs = (const float*)d_in[0];
    const float* ps     = (const float*)d_in[1];
    const float* labels = (const float*)d_in[2];
    const float* rois   = (const float*)d_in[3];
    const float* fcw    = (const float*)d_in[4];
    const float* fcb    = (const float*)d_in[5];

    int B = in_sizes[2] / 4;            // 16
    int rows = B * PCNT;                // 32768
    float* out = (float*)d_out;

    char* ws = (char*)d_ws;
    size_t off = 0;
    unsigned long long* keys = (unsigned long long*)(ws + off);
    int nkeys = rows * 3;
    off += (size_t)nkeys * 8;
    off = (off + 255) & ~(size_t)255;
    float* partials = (float*)(ws + off);               off += 128 * 8 * 4;
    unsigned* doneCnt = (unsigned*)(ws + off);          off += 256;
    int* seedsCnt  = (int*)(ws + off);                  off += (size_t)B * 3 * 4;
    int* seedsAmax = (int*)(ws + off);                  off += (size_t)B * 3 * 4;
    off = (off + 255) & ~(size_t)255;
    int* cellCnt   = (int*)(ws + off);                  off += (size_t)B * 64 * 4;
    int* cellStart = (int*)(ws + off);                  off += (size_t)B * 64 * 4;
    off = (off + 255) & ~(size_t)255;
    float4* roisE = (float4*)(ws + off);                off += (size_t)B * CAP_B * 16;
    float4* metaE = (float4*)(ws + off);                off += (size_t)B * CAP_B * 16;
    bool binned = (ws_size >= off);

    int gemvBlocks = rows / 16;   // 2048
    const int NBLK = 128;         // rows/256
    if (binned) {
        k_mega<<<gemvBlocks + 3 * B + 8 * B, 256, 0, stream>>>(
            inputs, fcw, fcb, out, keys, nkeys, doneCnt,
            ps, seedsCnt, seedsAmax, rois, cellCnt, gemvBlocks, B);
        k_scan_scatter<<<B, 256, 0, stream>>>(rois, ps, seedsCnt, seedsAmax,
                                              cellCnt, cellStart, roisE, metaE);
        k_assign3<<<B * 64, 256, 0, stream>>>(cellCnt, cellStart, roisE, metaE, keys);
    } else {
        k_mega<<<gemvBlocks + 3 * B, 256, 0, stream>>>(
            inputs, fcw, fcb, out, keys, nkeys, doneCnt,
            ps, seedsCnt, seedsAmax, rois, cellCnt, gemvBlocks, B);
        k_assign_fallback<<<B * 64, 256, 0, stream>>>(rois, ps, seedsCnt, seedsAmax, keys);
    }
    k_finalize_loss<<<NBLK, 256, 0, stream>>>(keys, ps, labels, out, partials,
                                              doneCnt, out + (size_t)rows * 4,
                                              rows, 1.f / (float)B);
}